// Round 4
// baseline (473.254 us; speedup 1.0000x reference)
//
#include <hip/hip_runtime.h>
#include <hip/hip_bf16.h>
#include <stdint.h>

// Problem dims (fixed)
#define BB 4
#define TT 1024
#define SS 1024
#define EE 768      // embed dim = H*D
#define HH 12
#define DDIM 64
#define MM 3072
#define NROWS 4096  // B*T
#define ATT_SCALE 0.125f

typedef unsigned short u16;
using short8 = __attribute__((ext_vector_type(8))) short;
using f32x4  = __attribute__((ext_vector_type(4))) float;

__device__ inline f32x4 mfma16(short8 a, short8 b, f32x4 c) {
  return __builtin_amdgcn_mfma_f32_16x16x32_bf16(a, b, c, 0, 0, 0);
}

__device__ inline float b2f(u16 u) {
  union { uint32_t i; float f; } z; z.i = ((uint32_t)u) << 16; return z.f;
}
__device__ inline u16 f2b(float f) {
  __hip_bfloat16 h = __float2bfloat16(f);
  return *reinterpret_cast<u16*>(&h);
}
__device__ inline float loadf(const float* p) { return *p; }
__device__ inline float loadf(const u16* p) { return b2f(*p); }

__device__ inline float gelu_f(float x) {
  const float k0 = 0.7978845608028654f; // sqrt(2/pi)
  const float k1 = 0.044715f;
  float t = tanhf(k0 * (x + k1 * x * x * x));
  return 0.5f * x * (1.0f + t);
}

// async global->LDS, 16B per lane
__device__ inline void gload16(const u16* g, u16* l) {
  __builtin_amdgcn_global_load_lds(
      (const __attribute__((address_space(1))) unsigned int*)g,
      (__attribute__((address_space(3))) unsigned int*)l, 16, 0, 0);
}

// ------- transpose+convert: in fp32 [batch][R][C] -> out bf16 [batch][C][R] -
__global__ void transpose_k(const float* __restrict__ in, u16* __restrict__ out,
                            int R, int C) {
  __shared__ u16 tile[32][34];
  int bz = blockIdx.z;
  const float* ip = in + (size_t)bz * R * C;
  u16* op = out + (size_t)bz * R * C;
  int r0 = blockIdx.y * 32, c0 = blockIdx.x * 32;
  int tx = threadIdx.x, ty = threadIdx.y; // 32 x 8
#pragma unroll
  for (int j = 0; j < 32; j += 8)
    tile[ty + j][tx] = f2b(ip[(size_t)(r0 + ty + j) * C + (c0 + tx)]);
  __syncthreads();
#pragma unroll
  for (int j = 0; j < 32; j += 8)
    op[(size_t)(c0 + ty + j) * R + (r0 + tx)] = tile[tx][ty + j];
}

// ------- bf16 strided batched transpose: per-bz [R=1024 x C=64] -> [64][1024]
__global__ void tr_v_k(const u16* __restrict__ in, u16* __restrict__ out,
                       int ldi, size_t in_bstride) {
  __shared__ u16 tile[32][34];
  int bz = blockIdx.z;                 // b*HH + h
  const u16* ip = in + (size_t)(bz / HH) * in_bstride + (size_t)(bz % HH) * DDIM;
  u16* op = out + (size_t)bz * DDIM * SS;
  int r0 = blockIdx.y * 32, c0 = blockIdx.x * 32;
  int tx = threadIdx.x, ty = threadIdx.y; // 32 x 8
#pragma unroll
  for (int j = 0; j < 32; j += 8)
    tile[ty + j][tx] = ip[(size_t)(r0 + ty + j) * ldi + (c0 + tx)];
  __syncthreads();
#pragma unroll
  for (int j = 0; j < 32; j += 8)
    op[(size_t)(c0 + ty + j) * SS + (r0 + tx)] = tile[tx][ty + j];
}

// ------- fp32 -> bf16 convert (vector4) -----------------------------------
__global__ void cvt_k(const float* __restrict__ in, u16* __restrict__ out, int n) {
  int i = (blockIdx.x * 256 + threadIdx.x) * 4;
  if (i < n) {
    float4 f = *(const float4*)(in + i);
    u16 o[4] = {f2b(f.x), f2b(f.y), f2b(f.z), f2b(f.w)};
    *(uint64_t*)(out + i) = *(const uint64_t*)o;
  }
}

// ------- bias packing ------------------------------------------------------
__global__ void pack3_k(const float* __restrict__ a, const float* __restrict__ b,
                        const float* __restrict__ c, float* __restrict__ d) {
  int i = blockIdx.x * 256 + threadIdx.x; // grid 9 -> 2304
  if (i < 768) d[i] = a[i];
  else if (i < 1536) d[i] = b[i - 768];
  else d[i] = c[i - 1536];
}
__global__ void pack2_k(const float* __restrict__ a, const float* __restrict__ b,
                        float* __restrict__ d) {
  int i = blockIdx.x * 256 + threadIdx.x; // grid 6 -> 1536
  if (i < 768) d[i] = a[i];
  else d[i] = b[i - 768];
}

// ---------------- LayerNorm over last dim 768 -> bf16 out -------------------
template <typename T>
__global__ __launch_bounds__(256) void layernorm_k(const T* __restrict__ x,
    const float* __restrict__ g, const float* __restrict__ b,
    u16* __restrict__ y) {
  int row = blockIdx.x, t = threadIdx.x;
  const T* xr = x + (size_t)row * EE;
  float v0 = loadf(xr + t), v1 = loadf(xr + t + 256), v2 = loadf(xr + t + 512);
  float s = v0 + v1 + v2;
#pragma unroll
  for (int m = 32; m >= 1; m >>= 1) s += __shfl_xor(s, m);
  __shared__ float red[8];
  int wv = t >> 6, ln = t & 63;
  if (ln == 0) red[wv] = s;
  __syncthreads();
  float mean = (red[0] + red[1] + red[2] + red[3]) * (1.0f / EE);
  float d0 = v0 - mean, d1 = v1 - mean, d2 = v2 - mean;
  float s2 = d0 * d0 + d1 * d1 + d2 * d2;
#pragma unroll
  for (int m = 32; m >= 1; m >>= 1) s2 += __shfl_xor(s2, m);
  if (ln == 0) red[4 + wv] = s2;
  __syncthreads();
  float var = (red[4] + red[5] + red[6] + red[7]) * (1.0f / EE);
  float rstd = rsqrtf(var + 1e-5f);
  u16* yr = y + (size_t)row * EE;
  yr[t]       = f2b(d0 * rstd * g[t]       + b[t]);
  yr[t + 256] = f2b(d1 * rstd * g[t + 256] + b[t + 256]);
  yr[t + 512] = f2b(d2 * rstd * g[t + 512] + b[t + 512]);
}

// ---------------- GEMM 128x128 (m97 structure): C = A @ Bt^T + bias ---------
// A bf16 [M][K], Bt bf16 [N][K]. 256 thr = 4 waves (2x2), each 64x64.
// RESMODE: 0 none, 1 fp32 residual, 2 bf16 residual. ld of res/C = N.
template <int RESMODE, bool GELU, typename OutT>
__global__ __launch_bounds__(256) void gemm128_k(
    const u16* __restrict__ A, const u16* __restrict__ Bt,
    const float* __restrict__ bias, const void* __restrict__ res,
    OutT* __restrict__ C, int M, int N, int K) {
  __shared__ u16 As[128 * 32];  // linear row-major [128][32]
  __shared__ u16 Bs[128 * 32];
  const int bm = blockIdx.y * 128, bn = blockIdx.x * 128;
  const int t = threadIdx.x;
  const int wave = t >> 6, lane = t & 63;
  const int wr = wave >> 1, wc = wave & 1;
  const int g = lane >> 4, li = lane & 15;
  f32x4 acc[4][4] = {};
  const size_t rowskip = (size_t)64 * K;
  const u16* Ag = A + (size_t)(bm + (t >> 2)) * K + (t & 3) * 8;
  const u16* Bg = Bt + (size_t)(bn + (t >> 2)) * K + (t & 3) * 8;
  u16* lA = &As[t * 8];
  u16* lB = &Bs[t * 8];

  for (int k0 = 0; k0 < K; k0 += 32) {
    gload16(Ag + k0, lA);
    gload16(Ag + rowskip + k0, lA + 64 * 32);
    gload16(Bg + k0, lB);
    gload16(Bg + rowskip + k0, lB + 64 * 32);
    __syncthreads();
    short8 af[4], bf[4];
#pragma unroll
    for (int i = 0; i < 4; i++) {
      af[i] = *(const short8*)(&As[(wr * 64 + i * 16 + li) * 32 + g * 8]);
      bf[i] = *(const short8*)(&Bs[(wc * 64 + i * 16 + li) * 32 + g * 8]);
    }
#pragma unroll
    for (int mi = 0; mi < 4; mi++)
#pragma unroll
      for (int nj = 0; nj < 4; nj++)
        acc[mi][nj] = mfma16(af[mi], bf[nj], acc[mi][nj]);
    __syncthreads();
  }

#pragma unroll
  for (int mi = 0; mi < 4; mi++)
#pragma unroll
    for (int nj = 0; nj < 4; nj++) {
      int n = bn + wc * 64 + nj * 16 + li;
      float bv = bias[n];
#pragma unroll
      for (int i = 0; i < 4; i++) {
        int m = bm + wr * 64 + mi * 16 + g * 4 + i;
        float val = acc[mi][nj][i] + bv;
        if (GELU) val = gelu_f(val);
        if (RESMODE == 1) val += ((const float*)res)[(size_t)m * N + n];
        else if (RESMODE == 2) val += b2f(((const u16*)res)[(size_t)m * N + n]);
        if constexpr (sizeof(OutT) == 2) C[(size_t)m * N + n] = f2b(val);
        else                             C[(size_t)m * N + n] = val;
      }
    }
}

// ---------------- Flash attention v2: 1 wave/block, no block barriers -------
// Q rows [b*T+t][h*64+d] stride ldq; K rows stride ldk; VT [b*H+h][64 d][S t].
// grid (T/16, H, B), 64 threads.
template <bool CAUSAL>
__global__ __launch_bounds__(64) void attn2_k(
    const u16* __restrict__ Q, const u16* __restrict__ K,
    const u16* __restrict__ VT, u16* __restrict__ O,
    int ldq, int ldk) {
  int b = blockIdx.z, h = blockIdx.y, q0 = blockIdx.x * 16;
  int lane = threadIdx.x;
  int g = lane >> 4, li = lane & 15;
  const u16* Qb = Q + (size_t)b * TT * ldq + h * DDIM;
  const u16* Kb = K + (size_t)b * SS * ldk + h * DDIM;
  const u16* Vb = VT + (size_t)(b * HH + h) * DDIM * SS;  // [64][1024]
  u16* Ob = O + (size_t)b * TT * EE + h * DDIM;

  __shared__ u16 Ps[16][72];

  int qrow = q0 + li;
  short8 qf0 = *(const short8*)(Qb + (size_t)qrow * ldq + g * 8);
  short8 qf1 = *(const short8*)(Qb + (size_t)qrow * ldq + 32 + g * 8);

  f32x4 accO[4] = {};
  float mrow[4], lrow[4];
#pragma unroll
  for (int i = 0; i < 4; i++) { mrow[i] = -1e30f; lrow[i] = 0.f; }

  int kvEnd = CAUSAL ? ((int)(blockIdx.x >> 2) + 1) * 64 : SS;
  for (int kv0 = 0; kv0 < kvEnd; kv0 += 64) {
    // S = Q K^T : 16 q rows x 64 t cols
    f32x4 s[4];
#pragma unroll
    for (int kt = 0; kt < 4; kt++) {
      const u16* kr = Kb + (size_t)(kv0 + kt * 16 + li) * ldk;
      short8 kf0 = *(const short8*)(kr + g * 8);
      short8 kf1 = *(const short8*)(kr + 32 + g * 8);
      f32x4 z = {};
      z = mfma16(qf0, kf0, z);
      z = mfma16(qf1, kf1, z);
      s[kt] = z;
    }

    float rmax[4] = {-1e30f, -1e30f, -1e30f, -1e30f};
#pragma unroll
    for (int kt = 0; kt < 4; kt++)
#pragma unroll
      for (int i = 0; i < 4; i++) {
        float sv = s[kt][i] * ATT_SCALE;
        if (CAUSAL) {
          int qi = q0 + g * 4 + i;
          int ti = kv0 + kt * 16 + li;
          if (ti > qi) sv = -1e30f;
        }
        s[kt][i] = sv;
        rmax[i] = fmaxf(rmax[i], sv);
      }
#pragma unroll
    for (int msk = 1; msk < 16; msk <<= 1)
#pragma unroll
      for (int i = 0; i < 4; i++) rmax[i] = fmaxf(rmax[i], __shfl_xor(rmax[i], msk));

    float corr[4], rsum[4];
#pragma unroll
    for (int i = 0; i < 4; i++) {
      float mn = fmaxf(mrow[i], rmax[i]);
      corr[i] = __expf(mrow[i] - mn);
      mrow[i] = mn;
      rsum[i] = 0.f;
    }
#pragma unroll
    for (int kt = 0; kt < 4; kt++)
#pragma unroll
      for (int i = 0; i < 4; i++) {
        float sv = s[kt][i];
        float p = (sv < -1e29f) ? 0.f : __expf(sv - mrow[i]);
        s[kt][i] = p;
        rsum[i] += p;
      }
#pragma unroll
    for (int msk = 1; msk < 16; msk <<= 1)
#pragma unroll
      for (int i = 0; i < 4; i++) rsum[i] += __shfl_xor(rsum[i], msk);
#pragma unroll
    for (int i = 0; i < 4; i++) lrow[i] = lrow[i] * corr[i] + rsum[i];
#pragma unroll
    for (int dt = 0; dt < 4; dt++)
#pragma unroll
      for (int i = 0; i < 4; i++) accO[dt][i] *= corr[i];

    // P (bf16) -> per-wave LDS, re-read as A-fragments
#pragma unroll
    for (int kt = 0; kt < 4; kt++)
#pragma unroll
      for (int i = 0; i < 4; i++)
        Ps[g * 4 + i][kt * 16 + li] = f2b(s[kt][i]);

#pragma unroll
    for (int tc = 0; tc < 2; tc++) {
      short8 pf = *(const short8*)(&Ps[li][tc * 32 + g * 8]);
#pragma unroll
      for (int dt = 0; dt < 4; dt++) {
        short8 vf = *(const short8*)(Vb + (size_t)(dt * 16 + li) * SS + kv0 + tc * 32 + g * 8);
        accO[dt] = mfma16(pf, vf, accO[dt]);
      }
    }
  }

#pragma unroll
  for (int i = 0; i < 4; i++) {
    float inv = 1.0f / lrow[i];
    int q = q0 + g * 4 + i;
#pragma unroll
    for (int dt = 0; dt < 4; dt++)
      Ob[(size_t)q * EE + dt * 16 + li] = f2b(accO[dt][i] * inv);
  }
}

// ---------------------------------------------------------------------------
static inline void* wsoff(void* ws, size_t& off, size_t bytes) {
  void* p = (char*)ws + off;
  off += (bytes + 255) & ~(size_t)255;
  return p;
}

extern "C" void kernel_launch(void* const* d_in, const int* in_sizes, int n_in,
                              void* d_out, int out_size, void* d_ws, size_t ws_size,
                              hipStream_t stream) {
  const float* target = (const float*)d_in[0];
  const float* memory = (const float*)d_in[1];
  const float* sa_wq = (const float*)d_in[2];  const float* sa_bq = (const float*)d_in[3];
  const float* sa_wk = (const float*)d_in[4];  const float* sa_bk = (const float*)d_in[5];
  const float* sa_wv = (const float*)d_in[6];  const float* sa_bv = (const float*)d_in[7];
  const float* sa_wo = (const float*)d_in[8];  const float* sa_bo = (const float*)d_in[9];
  const float* ca_wq = (const float*)d_in[10]; const float* ca_bq = (const float*)d_in[11];
  const float* ca_wk = (const float*)d_in[12]; const float* ca_bk = (const float*)d_in[13];
  const float* ca_wv = (const float*)d_in[14]; const float* ca_bv = (const float*)d_in[15];
  const float* ca_wo = (const float*)d_in[16]; const float* ca_bo = (const float*)d_in[17];
  const float* ln1_g = (const float*)d_in[18]; const float* ln1_b = (const float*)d_in[19];
  const float* ln2_g = (const float*)d_in[20]; const float* ln2_b = (const float*)d_in[21];
  const float* ln3_g = (const float*)d_in[22]; const float* ln3_b = (const float*)d_in[23];
  const float* ffn_w1 = (const float*)d_in[24]; const float* ffn_b1 = (const float*)d_in[25];
  const float* ffn_w2 = (const float*)d_in[26]; const float* ffn_b2 = (const float*)d_in[27];

  // ---- workspace (~66 MB) ----
  size_t off = 0;
  const size_t WB = (size_t)EE * EE * 2;           // 1.125 MB
  u16* wqkvT_sa = (u16*)wsoff(d_ws, off, 3 * WB);  // [2304][768]
  u16* wqT_ca   = (u16*)wsoff(d_ws, off, WB);
  u16* wkvT_ca  = (u16*)wsoff(d_ws, off, 2 * WB);  // [1536][768]
  u16* woT_sa   = (u16*)wsoff(d_ws, off, WB);
  u16* woT_ca   = (u16*)wsoff(d_ws, off, WB);
  u16* w1T      = (u16*)wsoff(d_ws, off, (size_t)EE * MM * 2);
  u16* w2T      = (u16*)wsoff(d_ws, off, (size_t)EE * MM * 2);
  float* bsa_qkv = (float*)wsoff(d_ws, off, 2304 * 4);
  float* bca_kv  = (float*)wsoff(d_ws, off, 1536 * 4);
  const size_t AB = (size_t)NROWS * EE * 2;        // 6 MB
  u16* mx2   = (u16*)wsoff(d_ws, off, AB);         // memB (early) / x2 (late)
  u16* lnb   = (u16*)wsoff(d_ws, off, AB);         // S1
  u16* S2    = (u16*)wsoff(d_ws, off, 3 * AB);     // qkv_sa / (qb+kv_ca) / f1 head
  u16* S3    = (u16*)wsoff(d_ws, off, AB);         // attn_out / f1 tail
  u16* x1    = (u16*)wsoff(d_ws, off, AB);
  u16* vt    = (u16*)wsoff(d_ws, off, AB);         // V^T [B*H][64][1024]
  u16* qkv_sa = S2;                                // [4096][2304]
  u16* qb_ca  = S2;                                // [4096][768]
  u16* kv_ca  = S2 + (size_t)NROWS * EE;           // [4096][1536]
  u16* attn_out = S3;                              // [4096][768]
  u16* f1     = S2;                                // [4096][3072]
  u16* memB   = mx2;
  u16* x2     = mx2;

  dim3 tb(32, 8);
  // fp32->bf16 weight transposes: per-head [H][E][D]->[H*D][E]; [R][C]->[C][R]
  transpose_k<<<dim3(2, 24, 12), tb, 0, stream>>>(sa_wq, wqkvT_sa, EE, DDIM);
  transpose_k<<<dim3(2, 24, 12), tb, 0, stream>>>(sa_wk, wqkvT_sa + (size_t)EE * EE, EE, DDIM);
  transpose_k<<<dim3(2, 24, 12), tb, 0, stream>>>(sa_wv, wqkvT_sa + (size_t)2 * EE * EE, EE, DDIM);
  transpose_k<<<dim3(2, 24, 12), tb, 0, stream>>>(ca_wq, wqT_ca, EE, DDIM);
  transpose_k<<<dim3(2, 24, 12), tb, 0, stream>>>(ca_wk, wkvT_ca, EE, DDIM);
  transpose_k<<<dim3(2, 24, 12), tb, 0, stream>>>(ca_wv, wkvT_ca + (size_t)EE * EE, EE, DDIM);
  transpose_k<<<dim3(24, 24, 1), tb, 0, stream>>>(sa_wo, woT_sa, EE, EE);
  transpose_k<<<dim3(24, 24, 1), tb, 0, stream>>>(ca_wo, woT_ca, EE, EE);
  transpose_k<<<dim3(96, 24, 1), tb, 0, stream>>>(ffn_w1, w1T, EE, MM);
  transpose_k<<<dim3(24, 96, 1), tb, 0, stream>>>(ffn_w2, w2T, MM, EE);
  pack3_k<<<9, 256, 0, stream>>>(sa_bq, sa_bk, sa_bv, bsa_qkv);
  pack2_k<<<6, 256, 0, stream>>>(ca_bk, ca_bv, bca_kv);
  cvt_k<<<3072, 256, 0, stream>>>(memory, memB, NROWS * EE);

  // --- self-attention block ---
  layernorm_k<float><<<NROWS, 256, 0, stream>>>(target, ln1_g, ln1_b, lnb);
  gemm128_k<0, false, u16><<<dim3(18, 32), 256, 0, stream>>>(
      lnb, wqkvT_sa, bsa_qkv, nullptr, qkv_sa, NROWS, 3 * EE, EE);
  tr_v_k<<<dim3(2, 32, 48), tb, 0, stream>>>(qkv_sa + 2 * EE, vt, 3 * EE, (size_t)TT * 3 * EE);
  attn2_k<true><<<dim3(64, 12, 4), 64, 0, stream>>>(
      qkv_sa, qkv_sa + EE, vt, attn_out, 3 * EE, 3 * EE);
  gemm128_k<1, false, u16><<<dim3(6, 32), 256, 0, stream>>>(
      attn_out, woT_sa, sa_bo, target, x1, NROWS, EE, EE);

  // --- cross-attention block ---
  layernorm_k<u16><<<NROWS, 256, 0, stream>>>(x1, ln2_g, ln2_b, lnb);
  gemm128_k<0, false, u16><<<dim3(6, 32), 256, 0, stream>>>(
      lnb, wqT_ca, ca_bq, nullptr, qb_ca, NROWS, EE, EE);
  gemm128_k<0, false, u16><<<dim3(12, 32), 256, 0, stream>>>(
      memB, wkvT_ca, bca_kv, nullptr, kv_ca, NROWS, 2 * EE, EE);
  tr_v_k<<<dim3(2, 32, 48), tb, 0, stream>>>(kv_ca + EE, vt, 2 * EE, (size_t)SS * 2 * EE);
  attn2_k<false><<<dim3(64, 12, 4), 64, 0, stream>>>(
      qb_ca, kv_ca, vt, attn_out, EE, 2 * EE);
  gemm128_k<2, false, u16><<<dim3(6, 32), 256, 0, stream>>>(
      attn_out, woT_ca, ca_bo, x1, x2, NROWS, EE, EE);

  // --- FFN block ---
  layernorm_k<u16><<<NROWS, 256, 0, stream>>>(x2, ln3_g, ln3_b, lnb);
  gemm128_k<0, true, u16><<<dim3(24, 32), 256, 0, stream>>>(
      lnb, w1T, ffn_b1, nullptr, f1, NROWS, MM, EE);
  gemm128_k<2, false, float><<<dim3(6, 32), 256, 0, stream>>>(
      f1, w2T, ffn_b2, x2, (float*)d_out, NROWS, EE, MM);
}

// Round 5
// 393.851 us; speedup vs baseline: 1.2016x; 1.2016x over previous
//
#include <hip/hip_runtime.h>
#include <hip/hip_bf16.h>
#include <stdint.h>

// Problem dims (fixed)
#define BB 4
#define TT 1024
#define SS 1024
#define EE 768      // embed dim = H*D
#define HH 12
#define DDIM 64
#define MM 3072
#define NROWS 4096  // B*T
#define ATT_SCALE 0.125f

typedef unsigned short u16;
using short8 = __attribute__((ext_vector_type(8))) short;
using f32x4  = __attribute__((ext_vector_type(4))) float;

__device__ inline f32x4 mfma16(short8 a, short8 b, f32x4 c) {
  return __builtin_amdgcn_mfma_f32_16x16x32_bf16(a, b, c, 0, 0, 0);
}

__device__ inline float b2f(u16 u) {
  union { uint32_t i; float f; } z; z.i = ((uint32_t)u) << 16; return z.f;
}
__device__ inline u16 f2b(float f) {
  __hip_bfloat16 h = __float2bfloat16(f);
  return *reinterpret_cast<u16*>(&h);
}
__device__ inline float loadf(const float* p) { return *p; }
__device__ inline float loadf(const u16* p) { return b2f(*p); }

__device__ inline float gelu_f(float x) {
  const float k0 = 0.7978845608028654f; // sqrt(2/pi)
  const float k1 = 0.044715f;
  float t = tanhf(k0 * (x + k1 * x * x * x));
  return 0.5f * x * (1.0f + t);
}

// async global->LDS, 16B per lane
__device__ inline void gload16(const u16* g, u16* l) {
  __builtin_amdgcn_global_load_lds(
      (const __attribute__((address_space(1))) unsigned int*)g,
      (__attribute__((address_space(3))) unsigned int*)l, 16, 0, 0);
}

// ------- transpose+convert: in fp32 [batch][R][C] -> out bf16 [batch][C][R] -
__global__ void transpose_k(const float* __restrict__ in, u16* __restrict__ out,
                            int R, int C) {
  __shared__ u16 tile[32][34];
  int bz = blockIdx.z;
  const float* ip = in + (size_t)bz * R * C;
  u16* op = out + (size_t)bz * R * C;
  int r0 = blockIdx.y * 32, c0 = blockIdx.x * 32;
  int tx = threadIdx.x, ty = threadIdx.y; // 32 x 8
#pragma unroll
  for (int j = 0; j < 32; j += 8)
    tile[ty + j][tx] = f2b(ip[(size_t)(r0 + ty + j) * C + (c0 + tx)]);
  __syncthreads();
#pragma unroll
  for (int j = 0; j < 32; j += 8)
    op[(size_t)(c0 + ty + j) * R + (r0 + tx)] = tile[tx][ty + j];
}

// ------- bf16 strided batched transpose: per-bz [R=1024 x C=64] -> [64][1024]
__global__ void tr_v_k(const u16* __restrict__ in, u16* __restrict__ out,
                       int ldi, size_t in_bstride) {
  __shared__ u16 tile[32][34];
  int bz = blockIdx.z;                 // b*HH + h
  const u16* ip = in + (size_t)(bz / HH) * in_bstride + (size_t)(bz % HH) * DDIM;
  u16* op = out + (size_t)bz * DDIM * SS;
  int r0 = blockIdx.y * 32, c0 = blockIdx.x * 32;
  int tx = threadIdx.x, ty = threadIdx.y; // 32 x 8
#pragma unroll
  for (int j = 0; j < 32; j += 8)
    tile[ty + j][tx] = ip[(size_t)(r0 + ty + j) * ldi + (c0 + tx)];
  __syncthreads();
#pragma unroll
  for (int j = 0; j < 32; j += 8)
    op[(size_t)(c0 + ty + j) * SS + (r0 + tx)] = tile[tx][ty + j];
}

// ------- fp32 -> bf16 convert (vector4) -----------------------------------
__global__ void cvt_k(const float* __restrict__ in, u16* __restrict__ out, int n) {
  int i = (blockIdx.x * 256 + threadIdx.x) * 4;
  if (i < n) {
    float4 f = *(const float4*)(in + i);
    u16 o[4] = {f2b(f.x), f2b(f.y), f2b(f.z), f2b(f.w)};
    *(uint64_t*)(out + i) = *(const uint64_t*)o;
  }
}

// ------- bias packing ------------------------------------------------------
__global__ void pack3_k(const float* __restrict__ a, const float* __restrict__ b,
                        const float* __restrict__ c, float* __restrict__ d) {
  int i = blockIdx.x * 256 + threadIdx.x; // grid 9 -> 2304
  if (i < 768) d[i] = a[i];
  else if (i < 1536) d[i] = b[i - 768];
  else d[i] = c[i - 1536];
}
__global__ void pack2_k(const float* __restrict__ a, const float* __restrict__ b,
                        float* __restrict__ d) {
  int i = blockIdx.x * 256 + threadIdx.x; // grid 6 -> 1536
  if (i < 768) d[i] = a[i];
  else d[i] = b[i - 768];
}

// ---------------- LayerNorm over last dim 768 -> bf16 out -------------------
template <typename T>
__global__ __launch_bounds__(256) void layernorm_k(const T* __restrict__ x,
    const float* __restrict__ g, const float* __restrict__ b,
    u16* __restrict__ y) {
  int row = blockIdx.x, t = threadIdx.x;
  const T* xr = x + (size_t)row * EE;
  float v0 = loadf(xr + t), v1 = loadf(xr + t + 256), v2 = loadf(xr + t + 512);
  float s = v0 + v1 + v2;
#pragma unroll
  for (int m = 32; m >= 1; m >>= 1) s += __shfl_xor(s, m);
  __shared__ float red[8];
  int wv = t >> 6, ln = t & 63;
  if (ln == 0) red[wv] = s;
  __syncthreads();
  float mean = (red[0] + red[1] + red[2] + red[3]) * (1.0f / EE);
  float d0 = v0 - mean, d1 = v1 - mean, d2 = v2 - mean;
  float s2 = d0 * d0 + d1 * d1 + d2 * d2;
#pragma unroll
  for (int m = 32; m >= 1; m >>= 1) s2 += __shfl_xor(s2, m);
  if (ln == 0) red[4 + wv] = s2;
  __syncthreads();
  float var = (red[4] + red[5] + red[6] + red[7]) * (1.0f / EE);
  float rstd = rsqrtf(var + 1e-5f);
  u16* yr = y + (size_t)row * EE;
  yr[t]       = f2b(d0 * rstd * g[t]       + b[t]);
  yr[t + 256] = f2b(d1 * rstd * g[t + 256] + b[t + 256]);
  yr[t + 512] = f2b(d2 * rstd * g[t + 512] + b[t + 512]);
}

// ---------------- GEMM 128x128 (m97 structure): C = A @ Bt^T + bias ---------
// A bf16 [M][K], Bt bf16 [N][K]. 256 thr = 4 waves (2x2), each 64x64.
// RESMODE: 0 none, 1 fp32 residual, 2 bf16 residual. ld of res/C = N.
template <int RESMODE, bool GELU, typename OutT>
__global__ __launch_bounds__(256) void gemm128_k(
    const u16* __restrict__ A, const u16* __restrict__ Bt,
    const float* __restrict__ bias, const void* __restrict__ res,
    OutT* __restrict__ C, int M, int N, int K) {
  __shared__ u16 As[128 * 32];  // linear row-major [128][32]
  __shared__ u16 Bs[128 * 32];
  const int bm = blockIdx.y * 128, bn = blockIdx.x * 128;
  const int t = threadIdx.x;
  const int wave = t >> 6, lane = t & 63;
  const int wr = wave >> 1, wc = wave & 1;
  const int g = lane >> 4, li = lane & 15;
  f32x4 acc[4][4] = {};
  const size_t rowskip = (size_t)64 * K;
  const u16* Ag = A + (size_t)(bm + (t >> 2)) * K + (t & 3) * 8;
  const u16* Bg = Bt + (size_t)(bn + (t >> 2)) * K + (t & 3) * 8;
  u16* lA = &As[t * 8];
  u16* lB = &Bs[t * 8];

  for (int k0 = 0; k0 < K; k0 += 32) {
    gload16(Ag + k0, lA);
    gload16(Ag + rowskip + k0, lA + 64 * 32);
    gload16(Bg + k0, lB);
    gload16(Bg + rowskip + k0, lB + 64 * 32);
    __syncthreads();
    short8 af[4], bf[4];
#pragma unroll
    for (int i = 0; i < 4; i++) {
      af[i] = *(const short8*)(&As[(wr * 64 + i * 16 + li) * 32 + g * 8]);
      bf[i] = *(const short8*)(&Bs[(wc * 64 + i * 16 + li) * 32 + g * 8]);
    }
#pragma unroll
    for (int mi = 0; mi < 4; mi++)
#pragma unroll
      for (int nj = 0; nj < 4; nj++)
        acc[mi][nj] = mfma16(af[mi], bf[nj], acc[mi][nj]);
    __syncthreads();
  }

#pragma unroll
  for (int mi = 0; mi < 4; mi++)
#pragma unroll
    for (int nj = 0; nj < 4; nj++) {
      int n = bn + wc * 64 + nj * 16 + li;
      float bv = bias[n];
#pragma unroll
      for (int i = 0; i < 4; i++) {
        int m = bm + wr * 64 + mi * 16 + g * 4 + i;
        float val = acc[mi][nj][i] + bv;
        if (GELU) val = gelu_f(val);
        if (RESMODE == 1) val += ((const float*)res)[(size_t)m * N + n];
        else if (RESMODE == 2) val += b2f(((const u16*)res)[(size_t)m * N + n]);
        if constexpr (sizeof(OutT) == 2) C[(size_t)m * N + n] = f2b(val);
        else                             C[(size_t)m * N + n] = val;
      }
    }
}

// ---------------- Flash attention v3: 4 waves/block, swizzled LDS K/V -------
// Q/K row layouts with strides ldq/ldk; VT [b*H+h][64 d][1024 t].
// grid (T/64, H, B), 256 threads; wave w owns q rows q0+w*16 .. +15.
// LDS tiles [64][64] bf16 (128B rows), XOR-swizzled: colByte ^= (row&7)<<4.
// gload16 writes linearly (dest = base+lane*16); the swizzle is applied to
// the per-lane GLOBAL source address; ds_reads apply the same XOR (rule 21).
template <bool CAUSAL>
__global__ __launch_bounds__(256) void attn3_k(
    const u16* __restrict__ Q, const u16* __restrict__ K,
    const u16* __restrict__ VT, u16* __restrict__ O,
    int ldq, int ldk) {
  int b = blockIdx.z, h = blockIdx.y, q0 = blockIdx.x * 64;
  int tid = threadIdx.x, wave = tid >> 6, lane = tid & 63;
  int g = lane >> 4, li = lane & 15;
  const u16* Qb = Q + (size_t)b * TT * ldq + h * DDIM;
  const u16* Kb = K + (size_t)b * SS * ldk + h * DDIM;
  const u16* Vb = VT + (size_t)(b * HH + h) * DDIM * SS;  // [64][1024]
  u16* Ob = O + (size_t)b * TT * EE + h * DDIM;

  __shared__ u16 Ks[64 * 64];     // [t][d] swizzled
  __shared__ u16 Vs[64 * 64];     // [d][t] swizzled
  __shared__ u16 Ps[4][16][72];   // per-wave P [q][t]

  int qrow = q0 + wave * 16 + li;
  short8 qf0 = *(const short8*)(Qb + (size_t)qrow * ldq + g * 8);
  short8 qf1 = *(const short8*)(Qb + (size_t)qrow * ldq + 32 + g * 8);

  f32x4 accO[4] = {};
  float mrow[4], lrow[4];
#pragma unroll
  for (int i = 0; i < 4; i++) { mrow[i] = -1e30f; lrow[i] = 0.f; }

  // staging coords: thread -> (row 0..31, swizzled col) ; covers 32 rows/issue
  const int srow = tid >> 3;                                // 0..31
  const int scol = ((tid & 7) * 8) ^ ((srow & 7) << 3);     // elements, swz
  const int swzr = (li & 7) << 3;                           // read-side XOR

  int kvEnd = CAUSAL ? (q0 + 64) : SS;
  for (int kv0 = 0; kv0 < kvEnd; kv0 += 64) {
    gload16(Kb + (size_t)(kv0 + srow) * ldk + scol,      &Ks[tid * 8]);
    gload16(Kb + (size_t)(kv0 + 32 + srow) * ldk + scol, &Ks[2048 + tid * 8]);
    gload16(Vb + (size_t)srow * SS + kv0 + scol,         &Vs[tid * 8]);
    gload16(Vb + (size_t)(32 + srow) * SS + kv0 + scol,  &Vs[2048 + tid * 8]);
    __syncthreads();

    // S = Q K^T : this wave's 16 q rows x 64 t cols
    f32x4 s[4];
#pragma unroll
    for (int kt = 0; kt < 4; kt++) {
      int kr = kt * 16 + li;
      short8 kf0 = *(const short8*)(&Ks[kr * 64 + ((g * 8) ^ swzr)]);
      short8 kf1 = *(const short8*)(&Ks[kr * 64 + ((g * 8 + 32) ^ swzr)]);
      f32x4 z = {};
      z = mfma16(qf0, kf0, z);
      z = mfma16(qf1, kf1, z);
      s[kt] = z;
    }

    float rmax[4] = {-1e30f, -1e30f, -1e30f, -1e30f};
#pragma unroll
    for (int kt = 0; kt < 4; kt++)
#pragma unroll
      for (int i = 0; i < 4; i++) {
        float sv = s[kt][i] * ATT_SCALE;
        if (CAUSAL) {
          int qi = q0 + wave * 16 + g * 4 + i;
          int ti = kv0 + kt * 16 + li;
          if (ti > qi) sv = -1e30f;
        }
        s[kt][i] = sv;
        rmax[i] = fmaxf(rmax[i], sv);
      }
#pragma unroll
    for (int msk = 1; msk < 16; msk <<= 1)
#pragma unroll
      for (int i = 0; i < 4; i++) rmax[i] = fmaxf(rmax[i], __shfl_xor(rmax[i], msk));

    float corr[4], rsum[4];
#pragma unroll
    for (int i = 0; i < 4; i++) {
      float mn = fmaxf(mrow[i], rmax[i]);
      corr[i] = __expf(mrow[i] - mn);
      mrow[i] = mn;
      rsum[i] = 0.f;
    }
#pragma unroll
    for (int kt = 0; kt < 4; kt++)
#pragma unroll
      for (int i = 0; i < 4; i++) {
        float sv = s[kt][i];
        float p = (sv < -1e29f) ? 0.f : __expf(sv - mrow[i]);
        s[kt][i] = p;
        rsum[i] += p;
      }
#pragma unroll
    for (int msk = 1; msk < 16; msk <<= 1)
#pragma unroll
      for (int i = 0; i < 4; i++) rsum[i] += __shfl_xor(rsum[i], msk);
#pragma unroll
    for (int i = 0; i < 4; i++) lrow[i] = lrow[i] * corr[i] + rsum[i];
#pragma unroll
    for (int dt = 0; dt < 4; dt++)
#pragma unroll
      for (int i = 0; i < 4; i++) accO[dt][i] *= corr[i];

    // P (bf16) -> per-wave LDS, re-read as A-fragments
#pragma unroll
    for (int kt = 0; kt < 4; kt++)
#pragma unroll
      for (int i = 0; i < 4; i++)
        Ps[wave][g * 4 + i][kt * 16 + li] = f2b(s[kt][i]);

#pragma unroll
    for (int tc = 0; tc < 2; tc++) {
      short8 pf = *(const short8*)(&Ps[wave][li][tc * 32 + g * 8]);
#pragma unroll
      for (int dt = 0; dt < 4; dt++) {
        int vr = dt * 16 + li;
        short8 vf = *(const short8*)(&Vs[vr * 64 + ((tc * 32 + g * 8) ^ swzr)]);
        accO[dt] = mfma16(pf, vf, accO[dt]);
      }
    }
    __syncthreads();
  }

#pragma unroll
  for (int i = 0; i < 4; i++) {
    float inv = 1.0f / lrow[i];
    int q = q0 + wave * 16 + g * 4 + i;
#pragma unroll
    for (int dt = 0; dt < 4; dt++)
      Ob[(size_t)q * EE + dt * 16 + li] = f2b(accO[dt][i] * inv);
  }
}

// ---------------------------------------------------------------------------
static inline void* wsoff(void* ws, size_t& off, size_t bytes) {
  void* p = (char*)ws + off;
  off += (bytes + 255) & ~(size_t)255;
  return p;
}

extern "C" void kernel_launch(void* const* d_in, const int* in_sizes, int n_in,
                              void* d_out, int out_size, void* d_ws, size_t ws_size,
                              hipStream_t stream) {
  const float* target = (const float*)d_in[0];
  const float* memory = (const float*)d_in[1];
  const float* sa_wq = (const float*)d_in[2];  const float* sa_bq = (const float*)d_in[3];
  const float* sa_wk = (const float*)d_in[4];  const float* sa_bk = (const float*)d_in[5];
  const float* sa_wv = (const float*)d_in[6];  const float* sa_bv = (const float*)d_in[7];
  const float* sa_wo = (const float*)d_in[8];  const float* sa_bo = (const float*)d_in[9];
  const float* ca_wq = (const float*)d_in[10]; const float* ca_bq = (const float*)d_in[11];
  const float* ca_wk = (const float*)d_in[12]; const float* ca_bk = (const float*)d_in[13];
  const float* ca_wv = (const float*)d_in[14]; const float* ca_bv = (const float*)d_in[15];
  const float* ca_wo = (const float*)d_in[16]; const float* ca_bo = (const float*)d_in[17];
  const float* ln1_g = (const float*)d_in[18]; const float* ln1_b = (const float*)d_in[19];
  const float* ln2_g = (const float*)d_in[20]; const float* ln2_b = (const float*)d_in[21];
  const float* ln3_g = (const float*)d_in[22]; const float* ln3_b = (const float*)d_in[23];
  const float* ffn_w1 = (const float*)d_in[24]; const float* ffn_b1 = (const float*)d_in[25];
  const float* ffn_w2 = (const float*)d_in[26]; const float* ffn_b2 = (const float*)d_in[27];

  // ---- workspace (~66 MB) ----
  size_t off = 0;
  const size_t WB = (size_t)EE * EE * 2;           // 1.125 MB
  u16* wqkvT_sa = (u16*)wsoff(d_ws, off, 3 * WB);  // [2304][768]
  u16* wqT_ca   = (u16*)wsoff(d_ws, off, WB);
  u16* wkvT_ca  = (u16*)wsoff(d_ws, off, 2 * WB);  // [1536][768]
  u16* woT_sa   = (u16*)wsoff(d_ws, off, WB);
  u16* woT_ca   = (u16*)wsoff(d_ws, off, WB);
  u16* w1T      = (u16*)wsoff(d_ws, off, (size_t)EE * MM * 2);
  u16* w2T      = (u16*)wsoff(d_ws, off, (size_t)EE * MM * 2);
  float* bsa_qkv = (float*)wsoff(d_ws, off, 2304 * 4);
  float* bca_kv  = (float*)wsoff(d_ws, off, 1536 * 4);
  const size_t AB = (size_t)NROWS * EE * 2;        // 6 MB
  u16* mx2   = (u16*)wsoff(d_ws, off, AB);         // memB (early) / x2 (late)
  u16* lnb   = (u16*)wsoff(d_ws, off, AB);         // S1
  u16* S2    = (u16*)wsoff(d_ws, off, 3 * AB);     // qkv_sa / (qb+kv_ca) / f1 head
  u16* S3    = (u16*)wsoff(d_ws, off, AB);         // attn_out / f1 tail
  u16* x1    = (u16*)wsoff(d_ws, off, AB);
  u16* vt    = (u16*)wsoff(d_ws, off, AB);         // V^T [B*H][64][1024]
  u16* qkv_sa = S2;                                // [4096][2304]
  u16* qb_ca  = S2;                                // [4096][768]
  u16* kv_ca  = S2 + (size_t)NROWS * EE;           // [4096][1536]
  u16* attn_out = S3;                              // [4096][768]
  u16* f1     = S2;                                // [4096][3072]
  u16* memB   = mx2;
  u16* x2     = mx2;

  dim3 tb(32, 8);
  // fp32->bf16 weight transposes: per-head [H][E][D]->[H*D][E]; [R][C]->[C][R]
  transpose_k<<<dim3(2, 24, 12), tb, 0, stream>>>(sa_wq, wqkvT_sa, EE, DDIM);
  transpose_k<<<dim3(2, 24, 12), tb, 0, stream>>>(sa_wk, wqkvT_sa + (size_t)EE * EE, EE, DDIM);
  transpose_k<<<dim3(2, 24, 12), tb, 0, stream>>>(sa_wv, wqkvT_sa + (size_t)2 * EE * EE, EE, DDIM);
  transpose_k<<<dim3(2, 24, 12), tb, 0, stream>>>(ca_wq, wqT_ca, EE, DDIM);
  transpose_k<<<dim3(2, 24, 12), tb, 0, stream>>>(ca_wk, wkvT_ca, EE, DDIM);
  transpose_k<<<dim3(2, 24, 12), tb, 0, stream>>>(ca_wv, wkvT_ca + (size_t)EE * EE, EE, DDIM);
  transpose_k<<<dim3(24, 24, 1), tb, 0, stream>>>(sa_wo, woT_sa, EE, EE);
  transpose_k<<<dim3(24, 24, 1), tb, 0, stream>>>(ca_wo, woT_ca, EE, EE);
  transpose_k<<<dim3(96, 24, 1), tb, 0, stream>>>(ffn_w1, w1T, EE, MM);
  transpose_k<<<dim3(24, 96, 1), tb, 0, stream>>>(ffn_w2, w2T, MM, EE);
  pack3_k<<<9, 256, 0, stream>>>(sa_bq, sa_bk, sa_bv, bsa_qkv);
  pack2_k<<<6, 256, 0, stream>>>(ca_bk, ca_bv, bca_kv);
  cvt_k<<<3072, 256, 0, stream>>>(memory, memB, NROWS * EE);

  // --- self-attention block ---
  layernorm_k<float><<<NROWS, 256, 0, stream>>>(target, ln1_g, ln1_b, lnb);
  gemm128_k<0, false, u16><<<dim3(18, 32), 256, 0, stream>>>(
      lnb, wqkvT_sa, bsa_qkv, nullptr, qkv_sa, NROWS, 3 * EE, EE);
  tr_v_k<<<dim3(2, 32, 48), tb, 0, stream>>>(qkv_sa + 2 * EE, vt, 3 * EE, (size_t)TT * 3 * EE);
  attn3_k<true><<<dim3(16, 12, 4), 256, 0, stream>>>(
      qkv_sa, qkv_sa + EE, vt, attn_out, 3 * EE, 3 * EE);
  gemm128_k<1, false, u16><<<dim3(6, 32), 256, 0, stream>>>(
      attn_out, woT_sa, sa_bo, target, x1, NROWS, EE, EE);

  // --- cross-attention block ---
  layernorm_k<u16><<<NROWS, 256, 0, stream>>>(x1, ln2_g, ln2_b, lnb);
  gemm128_k<0, false, u16><<<dim3(6, 32), 256, 0, stream>>>(
      lnb, wqT_ca, ca_bq, nullptr, qb_ca, NROWS, EE, EE);
  gemm128_k<0, false, u16><<<dim3(12, 32), 256, 0, stream>>>(
      memB, wkvT_ca, bca_kv, nullptr, kv_ca, NROWS, 2 * EE, EE);
  tr_v_k<<<dim3(2, 32, 48), tb, 0, stream>>>(kv_ca + EE, vt, 2 * EE, (size_t)SS * 2 * EE);
  attn3_k<false><<<dim3(16, 12, 4), 256, 0, stream>>>(
      qb_ca, kv_ca, vt, attn_out, EE, 2 * EE);
  gemm128_k<2, false, u16><<<dim3(6, 32), 256, 0, stream>>>(
      attn_out, woT_ca, ca_bo, x1, x2, NROWS, EE, EE);

  // --- FFN block ---
  layernorm_k<u16><<<NROWS, 256, 0, stream>>>(x2, ln3_g, ln3_b, lnb);
  gemm128_k<0, true, u16><<<dim3(24, 32), 256, 0, stream>>>(
      lnb, w1T, ffn_b1, nullptr, f1, NROWS, MM, EE);
  gemm128_k<2, false, float><<<dim3(6, 32), 256, 0, stream>>>(
      f1, w2T, ffn_b2, x2, (float*)d_out, NROWS, EE, MM);
}

// Round 6
// 372.332 us; speedup vs baseline: 1.2711x; 1.0578x over previous
//
#include <hip/hip_runtime.h>
#include <hip/hip_bf16.h>
#include <stdint.h>

// Problem dims (fixed)
#define BB 4
#define TT 1024
#define SS 1024
#define EE 768      // embed dim = H*D
#define HH 12
#define DDIM 64
#define MM 3072
#define NROWS 4096  // B*T
#define ATT_SCALE 0.125f

typedef unsigned short u16;
using short8 = __attribute__((ext_vector_type(8))) short;
using f32x4  = __attribute__((ext_vector_type(4))) float;

__device__ inline f32x4 mfma16(short8 a, short8 b, f32x4 c) {
  return __builtin_amdgcn_mfma_f32_16x16x32_bf16(a, b, c, 0, 0, 0);
}

__device__ inline float b2f(u16 u) {
  union { uint32_t i; float f; } z; z.i = ((uint32_t)u) << 16; return z.f;
}
__device__ inline u16 f2b(float f) {
  __hip_bfloat16 h = __float2bfloat16(f);
  return *reinterpret_cast<u16*>(&h);
}
__device__ inline float loadf(const float* p) { return *p; }
__device__ inline float loadf(const u16* p) { return b2f(*p); }

__device__ inline float gelu_f(float x) {
  const float k0 = 0.7978845608028654f; // sqrt(2/pi)
  const float k1 = 0.044715f;
  float t = tanhf(k0 * (x + k1 * x * x * x));
  return 0.5f * x * (1.0f + t);
}

// async global->LDS, 16B per lane
__device__ inline void gload16(const u16* g, u16* l) {
  __builtin_amdgcn_global_load_lds(
      (const __attribute__((address_space(1))) unsigned int*)g,
      (__attribute__((address_space(3))) unsigned int*)l, 16, 0, 0);
}

// ------- transpose+convert: in fp32 [batch][R][C] -> out bf16 [batch][C][R] -
__global__ void transpose_k(const float* __restrict__ in, u16* __restrict__ out,
                            int R, int C) {
  __shared__ u16 tile[32][34];
  int bz = blockIdx.z;
  const float* ip = in + (size_t)bz * R * C;
  u16* op = out + (size_t)bz * R * C;
  int r0 = blockIdx.y * 32, c0 = blockIdx.x * 32;
  int tx = threadIdx.x, ty = threadIdx.y; // 32 x 8
#pragma unroll
  for (int j = 0; j < 32; j += 8)
    tile[ty + j][tx] = f2b(ip[(size_t)(r0 + ty + j) * C + (c0 + tx)]);
  __syncthreads();
#pragma unroll
  for (int j = 0; j < 32; j += 8)
    op[(size_t)(c0 + ty + j) * R + (r0 + tx)] = tile[tx][ty + j];
}

// ------- bf16 strided batched transpose: per-bz [R=1024 x C=64] -> [64][1024]
__global__ void tr_v_k(const u16* __restrict__ in, u16* __restrict__ out,
                       int ldi, size_t in_bstride) {
  __shared__ u16 tile[32][34];
  int bz = blockIdx.z;                 // b*HH + h
  const u16* ip = in + (size_t)(bz / HH) * in_bstride + (size_t)(bz % HH) * DDIM;
  u16* op = out + (size_t)bz * DDIM * SS;
  int r0 = blockIdx.y * 32, c0 = blockIdx.x * 32;
  int tx = threadIdx.x, ty = threadIdx.y; // 32 x 8
#pragma unroll
  for (int j = 0; j < 32; j += 8)
    tile[ty + j][tx] = ip[(size_t)(r0 + ty + j) * ldi + (c0 + tx)];
  __syncthreads();
#pragma unroll
  for (int j = 0; j < 32; j += 8)
    op[(size_t)(c0 + ty + j) * SS + (r0 + tx)] = tile[tx][ty + j];
}

// ------- fp32 -> bf16 convert (vector4) -----------------------------------
__global__ void cvt_k(const float* __restrict__ in, u16* __restrict__ out, int n) {
  int i = (blockIdx.x * 256 + threadIdx.x) * 4;
  if (i < n) {
    float4 f = *(const float4*)(in + i);
    u16 o[4] = {f2b(f.x), f2b(f.y), f2b(f.z), f2b(f.w)};
    *(uint64_t*)(out + i) = *(const uint64_t*)o;
  }
}

// ------- init d_out = bf16(x2) + bias (residual+bias base for split-K) -----
__global__ void init_out_k(const u16* __restrict__ x2, const float* __restrict__ b,
                           float* __restrict__ out) {
  int i = (blockIdx.x * 256 + threadIdx.x) * 4;
  int n = i % EE;
#pragma unroll
  for (int j = 0; j < 4; j++)
    out[i + j] = b2f(x2[i + j]) + b[n + j];
}

// ------- bias packing ------------------------------------------------------
__global__ void pack3_k(const float* __restrict__ a, const float* __restrict__ b,
                        const float* __restrict__ c, float* __restrict__ d) {
  int i = blockIdx.x * 256 + threadIdx.x; // grid 9 -> 2304
  if (i < 768) d[i] = a[i];
  else if (i < 1536) d[i] = b[i - 768];
  else d[i] = c[i - 1536];
}
__global__ void pack2_k(const float* __restrict__ a, const float* __restrict__ b,
                        float* __restrict__ d) {
  int i = blockIdx.x * 256 + threadIdx.x; // grid 6 -> 1536
  if (i < 768) d[i] = a[i];
  else d[i] = b[i - 768];
}

// ---------------- LayerNorm over last dim 768 -> bf16 out -------------------
template <typename T>
__global__ __launch_bounds__(256) void layernorm_k(const T* __restrict__ x,
    const float* __restrict__ g, const float* __restrict__ b,
    u16* __restrict__ y) {
  int row = blockIdx.x, t = threadIdx.x;
  const T* xr = x + (size_t)row * EE;
  float v0 = loadf(xr + t), v1 = loadf(xr + t + 256), v2 = loadf(xr + t + 512);
  float s = v0 + v1 + v2;
#pragma unroll
  for (int m = 32; m >= 1; m >>= 1) s += __shfl_xor(s, m);
  __shared__ float red[8];
  int wv = t >> 6, ln = t & 63;
  if (ln == 0) red[wv] = s;
  __syncthreads();
  float mean = (red[0] + red[1] + red[2] + red[3]) * (1.0f / EE);
  float d0 = v0 - mean, d1 = v1 - mean, d2 = v2 - mean;
  float s2 = d0 * d0 + d1 * d1 + d2 * d2;
#pragma unroll
  for (int m = 32; m >= 1; m >>= 1) s2 += __shfl_xor(s2, m);
  if (ln == 0) red[4 + wv] = s2;
  __syncthreads();
  float var = (red[4] + red[5] + red[6] + red[7]) * (1.0f / EE);
  float rstd = rsqrtf(var + 1e-5f);
  u16* yr = y + (size_t)row * EE;
  yr[t]       = f2b(d0 * rstd * g[t]       + b[t]);
  yr[t + 256] = f2b(d1 * rstd * g[t + 256] + b[t + 256]);
  yr[t + 512] = f2b(d2 * rstd * g[t + 512] + b[t + 512]);
}

// ---------------- GEMM 128x128 (m97 structure): C = A @ Bt^T + bias ---------
// A bf16 [M][K], Bt bf16 [N][K]. 256 thr = 4 waves (2x2), each 64x64.
// RESMODE: 0 none, 1 fp32 residual, 2 bf16 residual. ld of res/C = N.
template <int RESMODE, bool GELU, typename OutT>
__global__ __launch_bounds__(256) void gemm128_k(
    const u16* __restrict__ A, const u16* __restrict__ Bt,
    const float* __restrict__ bias, const void* __restrict__ res,
    OutT* __restrict__ C, int M, int N, int K) {
  __shared__ u16 As[128 * 32];  // linear row-major [128][32]
  __shared__ u16 Bs[128 * 32];
  const int bm = blockIdx.y * 128, bn = blockIdx.x * 128;
  const int t = threadIdx.x;
  const int wave = t >> 6, lane = t & 63;
  const int wr = wave >> 1, wc = wave & 1;
  const int g = lane >> 4, li = lane & 15;
  f32x4 acc[4][4] = {};
  const size_t rowskip = (size_t)64 * K;
  const u16* Ag = A + (size_t)(bm + (t >> 2)) * K + (t & 3) * 8;
  const u16* Bg = Bt + (size_t)(bn + (t >> 2)) * K + (t & 3) * 8;
  u16* lA = &As[t * 8];
  u16* lB = &Bs[t * 8];

  for (int k0 = 0; k0 < K; k0 += 32) {
    gload16(Ag + k0, lA);
    gload16(Ag + rowskip + k0, lA + 64 * 32);
    gload16(Bg + k0, lB);
    gload16(Bg + rowskip + k0, lB + 64 * 32);
    __syncthreads();
    short8 af[4], bf[4];
#pragma unroll
    for (int i = 0; i < 4; i++) {
      af[i] = *(const short8*)(&As[(wr * 64 + i * 16 + li) * 32 + g * 8]);
      bf[i] = *(const short8*)(&Bs[(wc * 64 + i * 16 + li) * 32 + g * 8]);
    }
#pragma unroll
    for (int mi = 0; mi < 4; mi++)
#pragma unroll
      for (int nj = 0; nj < 4; nj++)
        acc[mi][nj] = mfma16(af[mi], bf[nj], acc[mi][nj]);
    __syncthreads();
  }

#pragma unroll
  for (int mi = 0; mi < 4; mi++)
#pragma unroll
    for (int nj = 0; nj < 4; nj++) {
      int n = bn + wc * 64 + nj * 16 + li;
      float bv = bias[n];
#pragma unroll
      for (int i = 0; i < 4; i++) {
        int m = bm + wr * 64 + mi * 16 + g * 4 + i;
        float val = acc[mi][nj][i] + bv;
        if (GELU) val = gelu_f(val);
        if (RESMODE == 1) val += ((const float*)res)[(size_t)m * N + n];
        else if (RESMODE == 2) val += b2f(((const u16*)res)[(size_t)m * N + n]);
        if constexpr (sizeof(OutT) == 2) C[(size_t)m * N + n] = f2b(val);
        else                             C[(size_t)m * N + n] = val;
      }
    }
}

// ---------------- split-K GEMM: atomic fp32 accumulate into C --------------
// grid (N/128, M/128, SPLITK); z owns K-chunk of length K/SPLITK.
template <int SPLITK>
__global__ __launch_bounds__(256) void gemm_sk_k(
    const u16* __restrict__ A, const u16* __restrict__ Bt,
    float* __restrict__ C, int M, int N, int K) {
  __shared__ u16 As[128 * 32];
  __shared__ u16 Bs[128 * 32];
  const int bm = blockIdx.y * 128, bn = blockIdx.x * 128;
  const int kchunk = K / SPLITK;
  const int kbase = blockIdx.z * kchunk;
  const int t = threadIdx.x;
  const int wave = t >> 6, lane = t & 63;
  const int wr = wave >> 1, wc = wave & 1;
  const int g = lane >> 4, li = lane & 15;
  f32x4 acc[4][4] = {};
  const size_t rowskip = (size_t)64 * K;
  const u16* Ag = A + (size_t)(bm + (t >> 2)) * K + (t & 3) * 8 + kbase;
  const u16* Bg = Bt + (size_t)(bn + (t >> 2)) * K + (t & 3) * 8 + kbase;
  u16* lA = &As[t * 8];
  u16* lB = &Bs[t * 8];

  for (int k0 = 0; k0 < kchunk; k0 += 32) {
    gload16(Ag + k0, lA);
    gload16(Ag + rowskip + k0, lA + 64 * 32);
    gload16(Bg + k0, lB);
    gload16(Bg + rowskip + k0, lB + 64 * 32);
    __syncthreads();
    short8 af[4], bf[4];
#pragma unroll
    for (int i = 0; i < 4; i++) {
      af[i] = *(const short8*)(&As[(wr * 64 + i * 16 + li) * 32 + g * 8]);
      bf[i] = *(const short8*)(&Bs[(wc * 64 + i * 16 + li) * 32 + g * 8]);
    }
#pragma unroll
    for (int mi = 0; mi < 4; mi++)
#pragma unroll
      for (int nj = 0; nj < 4; nj++)
        acc[mi][nj] = mfma16(af[mi], bf[nj], acc[mi][nj]);
    __syncthreads();
  }

#pragma unroll
  for (int mi = 0; mi < 4; mi++)
#pragma unroll
    for (int nj = 0; nj < 4; nj++) {
      int n = bn + wc * 64 + nj * 16 + li;
#pragma unroll
      for (int i = 0; i < 4; i++) {
        int m = bm + wr * 64 + mi * 16 + g * 4 + i;
        unsafeAtomicAdd(&C[(size_t)m * N + n], acc[mi][nj][i]);
      }
    }
}

// ---------------- Flash attention v4: KVBLK=128, swizzled LDS K/V ----------
// Q/K row layouts with strides ldq/ldk; VT [b*H+h][64 d][1024 t].
// grid (T/64, H, B), 256 threads; wave w owns q rows q0+w*16 .. +15.
// Ks [128][64] rows 128B swz (row&7)<<4 bytes; Vs [64][128] rows 256B swz
// (row&15)<<4 bytes. gload16 dest linear; swizzle on global SOURCE + reads.
template <bool CAUSAL>
__global__ __launch_bounds__(256) void attn4_k(
    const u16* __restrict__ Q, const u16* __restrict__ K,
    const u16* __restrict__ VT, u16* __restrict__ O,
    int ldq, int ldk) {
  int b = blockIdx.z, h = blockIdx.y, q0 = blockIdx.x * 64;
  int tid = threadIdx.x, wave = tid >> 6, lane = tid & 63;
  int g = lane >> 4, li = lane & 15;
  const u16* Qb = Q + (size_t)b * TT * ldq + h * DDIM;
  const u16* Kb = K + (size_t)b * SS * ldk + h * DDIM;
  const u16* Vb = VT + (size_t)(b * HH + h) * DDIM * SS;  // [64][1024]
  u16* Ob = O + (size_t)b * TT * EE + h * DDIM;

  __shared__ u16 Ks[128 * 64];
  __shared__ u16 Vs[64 * 128];
  __shared__ u16 Ps[4][16][132];

  int qrow = q0 + wave * 16 + li;
  short8 qf0 = *(const short8*)(Qb + (size_t)qrow * ldq + g * 8);
  short8 qf1 = *(const short8*)(Qb + (size_t)qrow * ldq + 32 + g * 8);

  f32x4 accO[4] = {};
  float mrow[4], lrow[4];
#pragma unroll
  for (int i = 0; i < 4; i++) { mrow[i] = -1e30f; lrow[i] = 0.f; }

  // staging coords
  const int krow = tid >> 3;                                  // 0..31 (+32j)
  const int vrow = tid >> 4;                                  // 0..15 (+16j)
  const int qmax = q0 + wave * 16 + 15;

  int kvEnd = CAUSAL ? (((q0 + 64 + 127) >> 7) << 7) : SS;
  for (int kv0 = 0; kv0 < kvEnd; kv0 += 128) {
#pragma unroll
    for (int j = 0; j < 4; j++) {
      int kr = j * 32 + krow;
      int kc = ((tid & 7) * 8) ^ ((kr & 7) << 3);
      gload16(Kb + (size_t)(kv0 + kr) * ldk + kc, &Ks[j * 2048 + tid * 8]);
    }
#pragma unroll
    for (int j = 0; j < 4; j++) {
      int vr = j * 16 + vrow;
      int vc = ((tid & 15) * 8) ^ ((vr & 15) << 3);
      gload16(Vb + (size_t)vr * SS + kv0 + vc, &Vs[j * 2048 + tid * 8]);
    }
    __syncthreads();

    if (!CAUSAL || kv0 <= qmax) {
      // S = Q K^T : this wave's 16 q rows x 128 t cols
      f32x4 s[8];
#pragma unroll
      for (int kt = 0; kt < 8; kt++) {
        int kr = kt * 16 + li;
        int sw = (kr & 7) << 3;
        short8 kf0 = *(const short8*)(&Ks[kr * 64 + ((g * 8) ^ sw)]);
        short8 kf1 = *(const short8*)(&Ks[kr * 64 + ((g * 8 + 32) ^ sw)]);
        f32x4 z = {};
        z = mfma16(qf0, kf0, z);
        z = mfma16(qf1, kf1, z);
        s[kt] = z;
      }

      float rmax[4] = {-1e30f, -1e30f, -1e30f, -1e30f};
#pragma unroll
      for (int kt = 0; kt < 8; kt++)
#pragma unroll
        for (int i = 0; i < 4; i++) {
          float sv = s[kt][i] * ATT_SCALE;
          if (CAUSAL) {
            int qi = q0 + wave * 16 + g * 4 + i;
            int ti = kv0 + kt * 16 + li;
            if (ti > qi) sv = -1e30f;
          }
          s[kt][i] = sv;
          rmax[i] = fmaxf(rmax[i], sv);
        }
#pragma unroll
      for (int msk = 1; msk < 16; msk <<= 1)
#pragma unroll
        for (int i = 0; i < 4; i++) rmax[i] = fmaxf(rmax[i], __shfl_xor(rmax[i], msk));

      float corr[4], rsum[4];
#pragma unroll
      for (int i = 0; i < 4; i++) {
        float mn = fmaxf(mrow[i], rmax[i]);
        corr[i] = __expf(mrow[i] - mn);
        mrow[i] = mn;
        rsum[i] = 0.f;
      }
#pragma unroll
      for (int kt = 0; kt < 8; kt++)
#pragma unroll
        for (int i = 0; i < 4; i++) {
          float sv = s[kt][i];
          float p = (sv < -1e29f) ? 0.f : __expf(sv - mrow[i]);
          s[kt][i] = p;
          rsum[i] += p;
        }
#pragma unroll
      for (int msk = 1; msk < 16; msk <<= 1)
#pragma unroll
        for (int i = 0; i < 4; i++) rsum[i] += __shfl_xor(rsum[i], msk);
#pragma unroll
      for (int i = 0; i < 4; i++) lrow[i] = lrow[i] * corr[i] + rsum[i];
#pragma unroll
      for (int dt = 0; dt < 4; dt++)
#pragma unroll
        for (int i = 0; i < 4; i++) accO[dt][i] *= corr[i];

      // P (bf16) -> per-wave LDS, re-read as A-fragments
#pragma unroll
      for (int kt = 0; kt < 8; kt++)
#pragma unroll
        for (int i = 0; i < 4; i++)
          Ps[wave][g * 4 + i][kt * 16 + li] = f2b(s[kt][i]);

#pragma unroll
      for (int tc = 0; tc < 4; tc++) {
        short8 pf = *(const short8*)(&Ps[wave][li][tc * 32 + g * 8]);
#pragma unroll
        for (int dt = 0; dt < 4; dt++) {
          int vr = dt * 16 + li;
          short8 vf = *(const short8*)(&Vs[vr * 128 + ((tc * 32 + g * 8) ^ ((vr & 15) << 3))]);
          accO[dt] = mfma16(pf, vf, accO[dt]);
        }
      }
    }
    __syncthreads();
  }

#pragma unroll
  for (int i = 0; i < 4; i++) {
    float inv = 1.0f / lrow[i];
    int q = q0 + wave * 16 + g * 4 + i;
#pragma unroll
    for (int dt = 0; dt < 4; dt++)
      Ob[(size_t)q * EE + dt * 16 + li] = f2b(accO[dt][i] * inv);
  }
}

// ---------------------------------------------------------------------------
static inline void* wsoff(void* ws, size_t& off, size_t bytes) {
  void* p = (char*)ws + off;
  off += (bytes + 255) & ~(size_t)255;
  return p;
}

extern "C" void kernel_launch(void* const* d_in, const int* in_sizes, int n_in,
                              void* d_out, int out_size, void* d_ws, size_t ws_size,
                              hipStream_t stream) {
  const float* target = (const float*)d_in[0];
  const float* memory = (const float*)d_in[1];
  const float* sa_wq = (const float*)d_in[2];  const float* sa_bq = (const float*)d_in[3];
  const float* sa_wk = (const float*)d_in[4];  const float* sa_bk = (const float*)d_in[5];
  const float* sa_wv = (const float*)d_in[6];  const float* sa_bv = (const float*)d_in[7];
  const float* sa_wo = (const float*)d_in[8];  const float* sa_bo = (const float*)d_in[9];
  const float* ca_wq = (const float*)d_in[10]; const float* ca_bq = (const float*)d_in[11];
  const float* ca_wk = (const float*)d_in[12]; const float* ca_bk = (const float*)d_in[13];
  const float* ca_wv = (const float*)d_in[14]; const float* ca_bv = (const float*)d_in[15];
  const float* ca_wo = (const float*)d_in[16]; const float* ca_bo = (const float*)d_in[17];
  const float* ln1_g = (const float*)d_in[18]; const float* ln1_b = (const float*)d_in[19];
  const float* ln2_g = (const float*)d_in[20]; const float* ln2_b = (const float*)d_in[21];
  const float* ln3_g = (const float*)d_in[22]; const float* ln3_b = (const float*)d_in[23];
  const float* ffn_w1 = (const float*)d_in[24]; const float* ffn_b1 = (const float*)d_in[25];
  const float* ffn_w2 = (const float*)d_in[26]; const float* ffn_b2 = (const float*)d_in[27];

  // ---- workspace (~66 MB) ----
  size_t off = 0;
  const size_t WB = (size_t)EE * EE * 2;           // 1.125 MB
  u16* wqkvT_sa = (u16*)wsoff(d_ws, off, 3 * WB);  // [2304][768]
  u16* wqT_ca   = (u16*)wsoff(d_ws, off, WB);
  u16* wkvT_ca  = (u16*)wsoff(d_ws, off, 2 * WB);  // [1536][768]
  u16* woT_sa   = (u16*)wsoff(d_ws, off, WB);
  u16* woT_ca   = (u16*)wsoff(d_ws, off, WB);
  u16* w1T      = (u16*)wsoff(d_ws, off, (size_t)EE * MM * 2);
  u16* w2T      = (u16*)wsoff(d_ws, off, (size_t)EE * MM * 2);
  float* bsa_qkv = (float*)wsoff(d_ws, off, 2304 * 4);
  float* bca_kv  = (float*)wsoff(d_ws, off, 1536 * 4);
  const size_t AB = (size_t)NROWS * EE * 2;        // 6 MB
  u16* mx2   = (u16*)wsoff(d_ws, off, AB);         // memB (early) / x2 (late)
  u16* lnb   = (u16*)wsoff(d_ws, off, AB);         // S1
  u16* S2    = (u16*)wsoff(d_ws, off, 3 * AB);     // qkv_sa / (qb+kv_ca) / f1 head
  u16* S3    = (u16*)wsoff(d_ws, off, AB);         // attn_out / f1 tail
  u16* x1    = (u16*)wsoff(d_ws, off, AB);
  u16* vt    = (u16*)wsoff(d_ws, off, AB);         // V^T [B*H][64][1024]
  u16* qkv_sa = S2;                                // [4096][2304]
  u16* qb_ca  = S2;                                // [4096][768]
  u16* kv_ca  = S2 + (size_t)NROWS * EE;           // [4096][1536]
  u16* attn_out = S3;                              // [4096][768]
  u16* f1     = S2;                                // [4096][3072]
  u16* memB   = mx2;
  u16* x2     = mx2;

  dim3 tb(32, 8);
  // fp32->bf16 weight transposes: per-head [H][E][D]->[H*D][E]; [R][C]->[C][R]
  transpose_k<<<dim3(2, 24, 12), tb, 0, stream>>>(sa_wq, wqkvT_sa, EE, DDIM);
  transpose_k<<<dim3(2, 24, 12), tb, 0, stream>>>(sa_wk, wqkvT_sa + (size_t)EE * EE, EE, DDIM);
  transpose_k<<<dim3(2, 24, 12), tb, 0, stream>>>(sa_wv, wqkvT_sa + (size_t)2 * EE * EE, EE, DDIM);
  transpose_k<<<dim3(2, 24, 12), tb, 0, stream>>>(ca_wq, wqT_ca, EE, DDIM);
  transpose_k<<<dim3(2, 24, 12), tb, 0, stream>>>(ca_wk, wkvT_ca, EE, DDIM);
  transpose_k<<<dim3(2, 24, 12), tb, 0, stream>>>(ca_wv, wkvT_ca + (size_t)EE * EE, EE, DDIM);
  transpose_k<<<dim3(24, 24, 1), tb, 0, stream>>>(sa_wo, woT_sa, EE, EE);
  transpose_k<<<dim3(24, 24, 1), tb, 0, stream>>>(ca_wo, woT_ca, EE, EE);
  transpose_k<<<dim3(96, 24, 1), tb, 0, stream>>>(ffn_w1, w1T, EE, MM);
  transpose_k<<<dim3(24, 96, 1), tb, 0, stream>>>(ffn_w2, w2T, MM, EE);
  pack3_k<<<9, 256, 0, stream>>>(sa_bq, sa_bk, sa_bv, bsa_qkv);
  pack2_k<<<6, 256, 0, stream>>>(ca_bk, ca_bv, bca_kv);
  cvt_k<<<3072, 256, 0, stream>>>(memory, memB, NROWS * EE);

  // --- self-attention block ---
  layernorm_k<float><<<NROWS, 256, 0, stream>>>(target, ln1_g, ln1_b, lnb);
  gemm128_k<0, false, u16><<<dim3(18, 32), 256, 0, stream>>>(
      lnb, wqkvT_sa, bsa_qkv, nullptr, qkv_sa, NROWS, 3 * EE, EE);
  tr_v_k<<<dim3(2, 32, 48), tb, 0, stream>>>(qkv_sa + 2 * EE, vt, 3 * EE, (size_t)TT * 3 * EE);
  attn4_k<true><<<dim3(16, 12, 4), 256, 0, stream>>>(
      qkv_sa, qkv_sa + EE, vt, attn_out, 3 * EE, 3 * EE);
  gemm128_k<1, false, u16><<<dim3(6, 32), 256, 0, stream>>>(
      attn_out, woT_sa, sa_bo, target, x1, NROWS, EE, EE);

  // --- cross-attention block ---
  layernorm_k<u16><<<NROWS, 256, 0, stream>>>(x1, ln2_g, ln2_b, lnb);
  gemm128_k<0, false, u16><<<dim3(6, 32), 256, 0, stream>>>(
      lnb, wqT_ca, ca_bq, nullptr, qb_ca, NROWS, EE, EE);
  gemm128_k<0, false, u16><<<dim3(12, 32), 256, 0, stream>>>(
      memB, wkvT_ca, bca_kv, nullptr, kv_ca, NROWS, 2 * EE, EE);
  tr_v_k<<<dim3(2, 32, 48), tb, 0, stream>>>(kv_ca + EE, vt, 2 * EE, (size_t)SS * 2 * EE);
  attn4_k<false><<<dim3(16, 12, 4), 256, 0, stream>>>(
      qb_ca, kv_ca, vt, attn_out, EE, 2 * EE);
  gemm128_k<2, false, u16><<<dim3(6, 32), 256, 0, stream>>>(
      attn_out, woT_ca, ca_bo, x1, x2, NROWS, EE, EE);

  // --- FFN block ---
  layernorm_k<u16><<<NROWS, 256, 0, stream>>>(x2, ln3_g, ln3_b, lnb);
  gemm128_k<0, true, u16><<<dim3(24, 32), 256, 0, stream>>>(
      lnb, w1T, ffn_b1, nullptr, f1, NROWS, MM, EE);
  // FFN2 via split-K=4 atomics: d_out = (x2 + b2) + sum_z partial_z
  init_out_k<<<3072, 256, 0, stream>>>(x2, ffn_b2, (float*)d_out);
  gemm_sk_k<4><<<dim3(6, 32, 4), 256, 0, stream>>>(
      f1, w2T, (float*)d_out, NROWS, EE, MM);
}

// Round 7
// 311.738 us; speedup vs baseline: 1.5181x; 1.1944x over previous
//
#include <hip/hip_runtime.h>
#include <hip/hip_bf16.h>
#include <stdint.h>

// Problem dims (fixed)
#define BB 4
#define TT 1024
#define SS 1024
#define EE 768      // embed dim = H*D
#define HH 12
#define DDIM 64
#define MM 3072
#define NROWS 4096  // B*T
#define ATT_SCALE 0.125f

typedef unsigned short u16;
using short8 = __attribute__((ext_vector_type(8))) short;
using f32x4  = __attribute__((ext_vector_type(4))) float;

__device__ inline f32x4 mfma16(short8 a, short8 b, f32x4 c) {
  return __builtin_amdgcn_mfma_f32_16x16x32_bf16(a, b, c, 0, 0, 0);
}

__device__ inline float b2f(u16 u) {
  union { uint32_t i; float f; } z; z.i = ((uint32_t)u) << 16; return z.f;
}
__device__ inline u16 f2b(float f) {
  __hip_bfloat16 h = __float2bfloat16(f);
  return *reinterpret_cast<u16*>(&h);
}
__device__ inline float loadf(const float* p) { return *p; }
__device__ inline float loadf(const u16* p) { return b2f(*p); }

__device__ inline float gelu_f(float x) {
  const float k0 = 0.7978845608028654f; // sqrt(2/pi)
  const float k1 = 0.044715f;
  float t = tanhf(k0 * (x + k1 * x * x * x));
  return 0.5f * x * (1.0f + t);
}

// async global->LDS, 16B per lane
__device__ inline void gload16(const u16* g, u16* l) {
  __builtin_amdgcn_global_load_lds(
      (const __attribute__((address_space(1))) unsigned int*)g,
      (__attribute__((address_space(3))) unsigned int*)l, 16, 0, 0);
}

// ------- transpose+convert: in fp32 [batch][R][C] -> out bf16 [batch][C][R] -
__global__ void transpose_k(const float* __restrict__ in, u16* __restrict__ out,
                            int R, int C) {
  __shared__ u16 tile[32][34];
  int bz = blockIdx.z;
  const float* ip = in + (size_t)bz * R * C;
  u16* op = out + (size_t)bz * R * C;
  int r0 = blockIdx.y * 32, c0 = blockIdx.x * 32;
  int tx = threadIdx.x, ty = threadIdx.y; // 32 x 8
#pragma unroll
  for (int j = 0; j < 32; j += 8)
    tile[ty + j][tx] = f2b(ip[(size_t)(r0 + ty + j) * C + (c0 + tx)]);
  __syncthreads();
#pragma unroll
  for (int j = 0; j < 32; j += 8)
    op[(size_t)(c0 + ty + j) * R + (r0 + tx)] = tile[tx][ty + j];
}

// ------- bf16 strided batched transpose: per-bz [R=1024 x C=64] -> [64][1024]
__global__ void tr_v_k(const u16* __restrict__ in, u16* __restrict__ out,
                       int ldi, size_t in_bstride) {
  __shared__ u16 tile[32][34];
  int bz = blockIdx.z;                 // b*HH + h
  const u16* ip = in + (size_t)(bz / HH) * in_bstride + (size_t)(bz % HH) * DDIM;
  u16* op = out + (size_t)bz * DDIM * SS;
  int r0 = blockIdx.y * 32, c0 = blockIdx.x * 32;
  int tx = threadIdx.x, ty = threadIdx.y; // 32 x 8
#pragma unroll
  for (int j = 0; j < 32; j += 8)
    tile[ty + j][tx] = ip[(size_t)(r0 + ty + j) * ldi + (c0 + tx)];
  __syncthreads();
#pragma unroll
  for (int j = 0; j < 32; j += 8)
    op[(size_t)(c0 + ty + j) * SS + (r0 + tx)] = tile[tx][ty + j];
}

// ------- fp32 -> bf16 convert (vector4) -----------------------------------
__global__ void cvt_k(const float* __restrict__ in, u16* __restrict__ out, int n) {
  int i = (blockIdx.x * 256 + threadIdx.x) * 4;
  if (i < n) {
    float4 f = *(const float4*)(in + i);
    u16 o[4] = {f2b(f.x), f2b(f.y), f2b(f.z), f2b(f.w)};
    *(uint64_t*)(out + i) = *(const uint64_t*)o;
  }
}

// ------- bias packing ------------------------------------------------------
__global__ void pack3_k(const float* __restrict__ a, const float* __restrict__ b,
                        const float* __restrict__ c, float* __restrict__ d) {
  int i = blockIdx.x * 256 + threadIdx.x; // grid 9 -> 2304
  if (i < 768) d[i] = a[i];
  else if (i < 1536) d[i] = b[i - 768];
  else d[i] = c[i - 1536];
}
__global__ void pack2_k(const float* __restrict__ a, const float* __restrict__ b,
                        float* __restrict__ d) {
  int i = blockIdx.x * 256 + threadIdx.x; // grid 6 -> 1536
  if (i < 768) d[i] = a[i];
  else d[i] = b[i - 768];
}

// ---------------- LayerNorm over last dim 768 -> bf16 out -------------------
template <typename T>
__global__ __launch_bounds__(256) void layernorm_k(const T* __restrict__ x,
    const float* __restrict__ g, const float* __restrict__ b,
    u16* __restrict__ y) {
  int row = blockIdx.x, t = threadIdx.x;
  const T* xr = x + (size_t)row * EE;
  float v0 = loadf(xr + t), v1 = loadf(xr + t + 256), v2 = loadf(xr + t + 512);
  float s = v0 + v1 + v2;
#pragma unroll
  for (int m = 32; m >= 1; m >>= 1) s += __shfl_xor(s, m);
  __shared__ float red[8];
  int wv = t >> 6, ln = t & 63;
  if (ln == 0) red[wv] = s;
  __syncthreads();
  float mean = (red[0] + red[1] + red[2] + red[3]) * (1.0f / EE);
  float d0 = v0 - mean, d1 = v1 - mean, d2 = v2 - mean;
  float s2 = d0 * d0 + d1 * d1 + d2 * d2;
#pragma unroll
  for (int m = 32; m >= 1; m >>= 1) s2 += __shfl_xor(s2, m);
  if (ln == 0) red[4 + wv] = s2;
  __syncthreads();
  float var = (red[4] + red[5] + red[6] + red[7]) * (1.0f / EE);
  float rstd = rsqrtf(var + 1e-5f);
  u16* yr = y + (size_t)row * EE;
  yr[t]       = f2b(d0 * rstd * g[t]       + b[t]);
  yr[t + 256] = f2b(d1 * rstd * g[t + 256] + b[t + 256]);
  yr[t + 512] = f2b(d2 * rstd * g[t + 512] + b[t + 512]);
}

// ---------------- GEMM 128x128 (m97 structure): C = A @ Bt^T + bias ---------
// A bf16 [M][K], Bt bf16 [N][K]. 256 thr = 4 waves (2x2), each 64x64.
// RESMODE: 0 none, 1 fp32 residual, 2 bf16 residual. ld of res/C = N.
template <int RESMODE, bool GELU, typename OutT>
__global__ __launch_bounds__(256) void gemm128_k(
    const u16* __restrict__ A, const u16* __restrict__ Bt,
    const float* __restrict__ bias, const void* __restrict__ res,
    OutT* __restrict__ C, int M, int N, int K) {
  __shared__ u16 As[128 * 32];  // linear row-major [128][32]
  __shared__ u16 Bs[128 * 32];
  const int bm = blockIdx.y * 128, bn = blockIdx.x * 128;
  const int t = threadIdx.x;
  const int wave = t >> 6, lane = t & 63;
  const int wr = wave >> 1, wc = wave & 1;
  const int g = lane >> 4, li = lane & 15;
  f32x4 acc[4][4] = {};
  const size_t rowskip = (size_t)64 * K;
  const u16* Ag = A + (size_t)(bm + (t >> 2)) * K + (t & 3) * 8;
  const u16* Bg = Bt + (size_t)(bn + (t >> 2)) * K + (t & 3) * 8;
  u16* lA = &As[t * 8];
  u16* lB = &Bs[t * 8];

  for (int k0 = 0; k0 < K; k0 += 32) {
    gload16(Ag + k0, lA);
    gload16(Ag + rowskip + k0, lA + 64 * 32);
    gload16(Bg + k0, lB);
    gload16(Bg + rowskip + k0, lB + 64 * 32);
    __syncthreads();
    short8 af[4], bf[4];
#pragma unroll
    for (int i = 0; i < 4; i++) {
      af[i] = *(const short8*)(&As[(wr * 64 + i * 16 + li) * 32 + g * 8]);
      bf[i] = *(const short8*)(&Bs[(wc * 64 + i * 16 + li) * 32 + g * 8]);
    }
#pragma unroll
    for (int mi = 0; mi < 4; mi++)
#pragma unroll
      for (int nj = 0; nj < 4; nj++)
        acc[mi][nj] = mfma16(af[mi], bf[nj], acc[mi][nj]);
    __syncthreads();
  }

#pragma unroll
  for (int mi = 0; mi < 4; mi++)
#pragma unroll
    for (int nj = 0; nj < 4; nj++) {
      int n = bn + wc * 64 + nj * 16 + li;
      float bv = bias[n];
#pragma unroll
      for (int i = 0; i < 4; i++) {
        int m = bm + wr * 64 + mi * 16 + g * 4 + i;
        float val = acc[mi][nj][i] + bv;
        if (GELU) val = gelu_f(val);
        if (RESMODE == 1) val += ((const float*)res)[(size_t)m * N + n];
        else if (RESMODE == 2) val += b2f(((const u16*)res)[(size_t)m * N + n]);
        if constexpr (sizeof(OutT) == 2) C[(size_t)m * N + n] = f2b(val);
        else                             C[(size_t)m * N + n] = val;
      }
    }
}

// ---------------- GEMM 64x64, BK=64, swizzled LDS (for small-N GEMMs) -------
// Grid (N/64, M/64): 4x the blocks of 128^2 -> hides per-K-step latency via
// inter-block overlap. LDS rows are 128B: XOR-swizzle (row&7)<<3 elems applied
// to global SOURCE (gload16 dest stays linear) and to ds_read col (rule 21).
template <int RESMODE, bool GELU, typename OutT>
__global__ __launch_bounds__(256) void gemm64_k(
    const u16* __restrict__ A, const u16* __restrict__ Bt,
    const float* __restrict__ bias, const void* __restrict__ res,
    OutT* __restrict__ C, int M, int N, int K) {
  __shared__ u16 As[64 * 64];   // [64 rows][64 k] row-major, swizzled content
  __shared__ u16 Bs[64 * 64];
  const int bm = blockIdx.y * 64, bn = blockIdx.x * 64;
  const int t = threadIdx.x;
  const int wave = t >> 6, lane = t & 63;
  const int wr = wave >> 1, wc = wave & 1;   // wave -> 32x32 quadrant
  const int g = lane >> 4, li = lane & 15;
  f32x4 acc[2][2] = {};
  // staging: issue j in {0,1}: row = (t>>3)+32j, col = (t&7)*8 (^ swizzle)
  const int srow = t >> 3;                           // 0..31
  const int scolz = ((t & 7) * 8) ^ ((srow & 7) << 3);
  const size_t skip32 = (size_t)32 * K;
  const u16* Ag = A + (size_t)(bm + srow) * K + scolz;
  const u16* Bg = Bt + (size_t)(bn + srow) * K + scolz;
  u16* lA = &As[t * 8];
  u16* lB = &Bs[t * 8];

  for (int k0 = 0; k0 < K; k0 += 64) {
    gload16(Ag + k0, lA);
    gload16(Ag + skip32 + k0, lA + 2048);
    gload16(Bg + k0, lB);
    gload16(Bg + skip32 + k0, lB + 2048);
    __syncthreads();
    short8 af[2][2], bf[2][2];
#pragma unroll
    for (int mt = 0; mt < 2; mt++)
#pragma unroll
      for (int kk = 0; kk < 2; kk++) {
        int ar = wr * 32 + mt * 16 + li;
        af[mt][kk] = *(const short8*)(&As[ar * 64 + ((kk * 32 + g * 8) ^ ((ar & 7) << 3))]);
        int br = wc * 32 + mt * 16 + li;
        bf[mt][kk] = *(const short8*)(&Bs[br * 64 + ((kk * 32 + g * 8) ^ ((br & 7) << 3))]);
      }
#pragma unroll
    for (int mt = 0; mt < 2; mt++)
#pragma unroll
      for (int nt = 0; nt < 2; nt++)
#pragma unroll
        for (int kk = 0; kk < 2; kk++)
          acc[mt][nt] = mfma16(af[mt][kk], bf[nt][kk], acc[mt][nt]);
    __syncthreads();
  }

#pragma unroll
  for (int mt = 0; mt < 2; mt++)
#pragma unroll
    for (int nt = 0; nt < 2; nt++) {
      int n = bn + wc * 32 + nt * 16 + li;
      float bv = bias[n];
#pragma unroll
      for (int i = 0; i < 4; i++) {
        int m = bm + wr * 32 + mt * 16 + g * 4 + i;
        float val = acc[mt][nt][i] + bv;
        if (GELU) val = gelu_f(val);
        if (RESMODE == 1) val += ((const float*)res)[(size_t)m * N + n];
        else if (RESMODE == 2) val += b2f(((const u16*)res)[(size_t)m * N + n]);
        if constexpr (sizeof(OutT) == 2) C[(size_t)m * N + n] = f2b(val);
        else                             C[(size_t)m * N + n] = val;
      }
    }
}

// ---------------- Flash attention v4: KVBLK=128, swizzled LDS K/V ----------
// Q/K row layouts with strides ldq/ldk; VT [b*H+h][64 d][1024 t].
// grid (T/64, H, B), 256 threads; wave w owns q rows q0+w*16 .. +15.
template <bool CAUSAL>
__global__ __launch_bounds__(256) void attn4_k(
    const u16* __restrict__ Q, const u16* __restrict__ K,
    const u16* __restrict__ VT, u16* __restrict__ O,
    int ldq, int ldk) {
  int b = blockIdx.z, h = blockIdx.y, q0 = blockIdx.x * 64;
  int tid = threadIdx.x, wave = tid >> 6, lane = tid & 63;
  int g = lane >> 4, li = lane & 15;
  const u16* Qb = Q + (size_t)b * TT * ldq + h * DDIM;
  const u16* Kb = K + (size_t)b * SS * ldk + h * DDIM;
  const u16* Vb = VT + (size_t)(b * HH + h) * DDIM * SS;  // [64][1024]
  u16* Ob = O + (size_t)b * TT * EE + h * DDIM;

  __shared__ u16 Ks[128 * 64];
  __shared__ u16 Vs[64 * 128];
  __shared__ u16 Ps[4][16][132];

  int qrow = q0 + wave * 16 + li;
  short8 qf0 = *(const short8*)(Qb + (size_t)qrow * ldq + g * 8);
  short8 qf1 = *(const short8*)(Qb + (size_t)qrow * ldq + 32 + g * 8);

  f32x4 accO[4] = {};
  float mrow[4], lrow[4];
#pragma unroll
  for (int i = 0; i < 4; i++) { mrow[i] = -1e30f; lrow[i] = 0.f; }

  // staging coords
  const int krow = tid >> 3;                                  // 0..31 (+32j)
  const int vrow = tid >> 4;                                  // 0..15 (+16j)
  const int qmax = q0 + wave * 16 + 15;

  int kvEnd = CAUSAL ? (((q0 + 64 + 127) >> 7) << 7) : SS;
  for (int kv0 = 0; kv0 < kvEnd; kv0 += 128) {
#pragma unroll
    for (int j = 0; j < 4; j++) {
      int kr = j * 32 + krow;
      int kc = ((tid & 7) * 8) ^ ((kr & 7) << 3);
      gload16(Kb + (size_t)(kv0 + kr) * ldk + kc, &Ks[j * 2048 + tid * 8]);
    }
#pragma unroll
    for (int j = 0; j < 4; j++) {
      int vr = j * 16 + vrow;
      int vc = ((tid & 15) * 8) ^ ((vr & 15) << 3);
      gload16(Vb + (size_t)vr * SS + kv0 + vc, &Vs[j * 2048 + tid * 8]);
    }
    __syncthreads();

    if (!CAUSAL || kv0 <= qmax) {
      // S = Q K^T : this wave's 16 q rows x 128 t cols
      f32x4 s[8];
#pragma unroll
      for (int kt = 0; kt < 8; kt++) {
        int kr = kt * 16 + li;
        int sw = (kr & 7) << 3;
        short8 kf0 = *(const short8*)(&Ks[kr * 64 + ((g * 8) ^ sw)]);
        short8 kf1 = *(const short8*)(&Ks[kr * 64 + ((g * 8 + 32) ^ sw)]);
        f32x4 z = {};
        z = mfma16(qf0, kf0, z);
        z = mfma16(qf1, kf1, z);
        s[kt] = z;
      }

      float rmax[4] = {-1e30f, -1e30f, -1e30f, -1e30f};
#pragma unroll
      for (int kt = 0; kt < 8; kt++)
#pragma unroll
        for (int i = 0; i < 4; i++) {
          float sv = s[kt][i] * ATT_SCALE;
          if (CAUSAL) {
            int qi = q0 + wave * 16 + g * 4 + i;
            int ti = kv0 + kt * 16 + li;
            if (ti > qi) sv = -1e30f;
          }
          s[kt][i] = sv;
          rmax[i] = fmaxf(rmax[i], sv);
        }
#pragma unroll
      for (int msk = 1; msk < 16; msk <<= 1)
#pragma unroll
        for (int i = 0; i < 4; i++) rmax[i] = fmaxf(rmax[i], __shfl_xor(rmax[i], msk));

      float corr[4], rsum[4];
#pragma unroll
      for (int i = 0; i < 4; i++) {
        float mn = fmaxf(mrow[i], rmax[i]);
        corr[i] = __expf(mrow[i] - mn);
        mrow[i] = mn;
        rsum[i] = 0.f;
      }
#pragma unroll
      for (int kt = 0; kt < 8; kt++)
#pragma unroll
        for (int i = 0; i < 4; i++) {
          float sv = s[kt][i];
          float p = (sv < -1e29f) ? 0.f : __expf(sv - mrow[i]);
          s[kt][i] = p;
          rsum[i] += p;
        }
#pragma unroll
      for (int msk = 1; msk < 16; msk <<= 1)
#pragma unroll
        for (int i = 0; i < 4; i++) rsum[i] += __shfl_xor(rsum[i], msk);
#pragma unroll
      for (int i = 0; i < 4; i++) lrow[i] = lrow[i] * corr[i] + rsum[i];
#pragma unroll
      for (int dt = 0; dt < 4; dt++)
#pragma unroll
        for (int i = 0; i < 4; i++) accO[dt][i] *= corr[i];

      // P (bf16) -> per-wave LDS, re-read as A-fragments
#pragma unroll
      for (int kt = 0; kt < 8; kt++)
#pragma unroll
        for (int i = 0; i < 4; i++)
          Ps[wave][g * 4 + i][kt * 16 + li] = f2b(s[kt][i]);

#pragma unroll
      for (int tc = 0; tc < 4; tc++) {
        short8 pf = *(const short8*)(&Ps[wave][li][tc * 32 + g * 8]);
#pragma unroll
        for (int dt = 0; dt < 4; dt++) {
          int vr = dt * 16 + li;
          short8 vf = *(const short8*)(&Vs[vr * 128 + ((tc * 32 + g * 8) ^ ((vr & 15) << 3))]);
          accO[dt] = mfma16(pf, vf, accO[dt]);
        }
      }
    }
    __syncthreads();
  }

#pragma unroll
  for (int i = 0; i < 4; i++) {
    float inv = 1.0f / lrow[i];
    int q = q0 + wave * 16 + g * 4 + i;
#pragma unroll
    for (int dt = 0; dt < 4; dt++)
      Ob[(size_t)q * EE + dt * 16 + li] = f2b(accO[dt][i] * inv);
  }
}

// ---------------------------------------------------------------------------
static inline void* wsoff(void* ws, size_t& off, size_t bytes) {
  void* p = (char*)ws + off;
  off += (bytes + 255) & ~(size_t)255;
  return p;
}

extern "C" void kernel_launch(void* const* d_in, const int* in_sizes, int n_in,
                              void* d_out, int out_size, void* d_ws, size_t ws_size,
                              hipStream_t stream) {
  const float* target = (const float*)d_in[0];
  const float* memory = (const float*)d_in[1];
  const float* sa_wq = (const float*)d_in[2];  const float* sa_bq = (const float*)d_in[3];
  const float* sa_wk = (const float*)d_in[4];  const float* sa_bk = (const float*)d_in[5];
  const float* sa_wv = (const float*)d_in[6];  const float* sa_bv = (const float*)d_in[7];
  const float* sa_wo = (const float*)d_in[8];  const float* sa_bo = (const float*)d_in[9];
  const float* ca_wq = (const float*)d_in[10]; const float* ca_bq = (const float*)d_in[11];
  const float* ca_wk = (const float*)d_in[12]; const float* ca_bk = (const float*)d_in[13];
  const float* ca_wv = (const float*)d_in[14]; const float* ca_bv = (const float*)d_in[15];
  const float* ca_wo = (const float*)d_in[16]; const float* ca_bo = (const float*)d_in[17];
  const float* ln1_g = (const float*)d_in[18]; const float* ln1_b = (const float*)d_in[19];
  const float* ln2_g = (const float*)d_in[20]; const float* ln2_b = (const float*)d_in[21];
  const float* ln3_g = (const float*)d_in[22]; const float* ln3_b = (const float*)d_in[23];
  const float* ffn_w1 = (const float*)d_in[24]; const float* ffn_b1 = (const float*)d_in[25];
  const float* ffn_w2 = (const float*)d_in[26]; const float* ffn_b2 = (const float*)d_in[27];

  // ---- workspace (~66 MB) ----
  size_t off = 0;
  const size_t WB = (size_t)EE * EE * 2;           // 1.125 MB
  u16* wqkvT_sa = (u16*)wsoff(d_ws, off, 3 * WB);  // [2304][768]
  u16* wqT_ca   = (u16*)wsoff(d_ws, off, WB);
  u16* wkvT_ca  = (u16*)wsoff(d_ws, off, 2 * WB);  // [1536][768]
  u16* woT_sa   = (u16*)wsoff(d_ws, off, WB);
  u16* woT_ca   = (u16*)wsoff(d_ws, off, WB);
  u16* w1T      = (u16*)wsoff(d_ws, off, (size_t)EE * MM * 2);
  u16* w2T      = (u16*)wsoff(d_ws, off, (size_t)EE * MM * 2);
  float* bsa_qkv = (float*)wsoff(d_ws, off, 2304 * 4);
  float* bca_kv  = (float*)wsoff(d_ws, off, 1536 * 4);
  const size_t AB = (size_t)NROWS * EE * 2;        // 6 MB
  u16* mx2   = (u16*)wsoff(d_ws, off, AB);         // memB (early) / x2 (late)
  u16* lnb   = (u16*)wsoff(d_ws, off, AB);         // S1
  u16* S2    = (u16*)wsoff(d_ws, off, 3 * AB);     // qkv_sa / (qb+kv_ca) / f1 head
  u16* S3    = (u16*)wsoff(d_ws, off, AB);         // attn_out / f1 tail
  u16* x1    = (u16*)wsoff(d_ws, off, AB);
  u16* vt    = (u16*)wsoff(d_ws, off, AB);         // V^T [B*H][64][1024]
  u16* qkv_sa = S2;                                // [4096][2304]
  u16* qb_ca  = S2;                                // [4096][768]
  u16* kv_ca  = S2 + (size_t)NROWS * EE;           // [4096][1536]
  u16* attn_out = S3;                              // [4096][768]
  u16* f1     = S2;                                // [4096][3072]
  u16* memB   = mx2;
  u16* x2     = mx2;

  dim3 tb(32, 8);
  // fp32->bf16 weight transposes: per-head [H][E][D]->[H*D][E]; [R][C]->[C][R]
  transpose_k<<<dim3(2, 24, 12), tb, 0, stream>>>(sa_wq, wqkvT_sa, EE, DDIM);
  transpose_k<<<dim3(2, 24, 12), tb, 0, stream>>>(sa_wk, wqkvT_sa + (size_t)EE * EE, EE, DDIM);
  transpose_k<<<dim3(2, 24, 12), tb, 0, stream>>>(sa_wv, wqkvT_sa + (size_t)2 * EE * EE, EE, DDIM);
  transpose_k<<<dim3(2, 24, 12), tb, 0, stream>>>(ca_wq, wqT_ca, EE, DDIM);
  transpose_k<<<dim3(2, 24, 12), tb, 0, stream>>>(ca_wk, wkvT_ca, EE, DDIM);
  transpose_k<<<dim3(2, 24, 12), tb, 0, stream>>>(ca_wv, wkvT_ca + (size_t)EE * EE, EE, DDIM);
  transpose_k<<<dim3(24, 24, 1), tb, 0, stream>>>(sa_wo, woT_sa, EE, EE);
  transpose_k<<<dim3(24, 24, 1), tb, 0, stream>>>(ca_wo, woT_ca, EE, EE);
  transpose_k<<<dim3(96, 24, 1), tb, 0, stream>>>(ffn_w1, w1T, EE, MM);
  transpose_k<<<dim3(24, 96, 1), tb, 0, stream>>>(ffn_w2, w2T, MM, EE);
  pack3_k<<<9, 256, 0, stream>>>(sa_bq, sa_bk, sa_bv, bsa_qkv);
  pack2_k<<<6, 256, 0, stream>>>(ca_bk, ca_bv, bca_kv);
  cvt_k<<<3072, 256, 0, stream>>>(memory, memB, NROWS * EE);

  // --- self-attention block ---
  layernorm_k<float><<<NROWS, 256, 0, stream>>>(target, ln1_g, ln1_b, lnb);
  gemm128_k<0, false, u16><<<dim3(18, 32), 256, 0, stream>>>(
      lnb, wqkvT_sa, bsa_qkv, nullptr, qkv_sa, NROWS, 3 * EE, EE);
  tr_v_k<<<dim3(2, 32, 48), tb, 0, stream>>>(qkv_sa + 2 * EE, vt, 3 * EE, (size_t)TT * 3 * EE);
  attn4_k<true><<<dim3(16, 12, 4), 256, 0, stream>>>(
      qkv_sa, qkv_sa + EE, vt, attn_out, 3 * EE, 3 * EE);
  gemm64_k<1, false, u16><<<dim3(12, 64), 256, 0, stream>>>(
      attn_out, woT_sa, sa_bo, target, x1, NROWS, EE, EE);

  // --- cross-attention block ---
  layernorm_k<u16><<<NROWS, 256, 0, stream>>>(x1, ln2_g, ln2_b, lnb);
  gemm64_k<0, false, u16><<<dim3(12, 64), 256, 0, stream>>>(
      lnb, wqT_ca, ca_bq, nullptr, qb_ca, NROWS, EE, EE);
  gemm64_k<0, false, u16><<<dim3(24, 64), 256, 0, stream>>>(
      memB, wkvT_ca, bca_kv, nullptr, kv_ca, NROWS, 2 * EE, EE);
  tr_v_k<<<dim3(2, 32, 48), tb, 0, stream>>>(kv_ca + EE, vt, 2 * EE, (size_t)SS * 2 * EE);
  attn4_k<false><<<dim3(16, 12, 4), 256, 0, stream>>>(
      qb_ca, kv_ca, vt, attn_out, EE, 2 * EE);
  gemm64_k<2, false, u16><<<dim3(12, 64), 256, 0, stream>>>(
      attn_out, woT_ca, ca_bo, x1, x2, NROWS, EE, EE);

  // --- FFN block ---
  layernorm_k<u16><<<NROWS, 256, 0, stream>>>(x2, ln3_g, ln3_b, lnb);
  gemm128_k<0, true, u16><<<dim3(24, 32), 256, 0, stream>>>(
      lnb, w1T, ffn_b1, nullptr, f1, NROWS, MM, EE);
  gemm64_k<2, false, float><<<dim3(12, 64), 256, 0, stream>>>(
      f1, w2T, ffn_b2, x2, (float*)d_out, NROWS, EE, MM);
}

// Round 8
// 300.649 us; speedup vs baseline: 1.5741x; 1.0369x over previous
//
#include <hip/hip_runtime.h>
#include <hip/hip_bf16.h>
#include <stdint.h>

// Problem dims (fixed)
#define BB 4
#define TT 1024
#define SS 1024
#define EE 768      // embed dim = H*D
#define HH 12
#define DDIM 64
#define MM 3072
#define NROWS 4096  // B*T
#define ATT_SCALE 0.125f

typedef unsigned short u16;
using short8 = __attribute__((ext_vector_type(8))) short;
using f32x4  = __attribute__((ext_vector_type(4))) float;

__device__ inline f32x4 mfma16(short8 a, short8 b, f32x4 c) {
  return __builtin_amdgcn_mfma_f32_16x16x32_bf16(a, b, c, 0, 0, 0);
}

__device__ inline float b2f(u16 u) {
  union { uint32_t i; float f; } z; z.i = ((uint32_t)u) << 16; return z.f;
}
__device__ inline u16 f2b(float f) {
  __hip_bfloat16 h = __float2bfloat16(f);
  return *reinterpret_cast<u16*>(&h);
}
__device__ inline float loadf(const float* p) { return *p; }
__device__ inline float loadf(const u16* p) { return b2f(*p); }

__device__ inline float gelu_f(float x) {
  const float k0 = 0.7978845608028654f; // sqrt(2/pi)
  const float k1 = 0.044715f;
  float t = tanhf(k0 * (x + k1 * x * x * x));
  return 0.5f * x * (1.0f + t);
}

// async global->LDS, 16B per lane
__device__ inline void gload16(const u16* g, u16* l) {
  __builtin_amdgcn_global_load_lds(
      (const __attribute__((address_space(1))) unsigned int*)g,
      (__attribute__((address_space(3))) unsigned int*)l, 16, 0, 0);
}

// ------- transpose+convert: in fp32 [batch][R][C] -> out bf16 [batch][C][R] -
__global__ void transpose_k(const float* __restrict__ in, u16* __restrict__ out,
                            int R, int C) {
  __shared__ u16 tile[32][34];
  int bz = blockIdx.z;
  const float* ip = in + (size_t)bz * R * C;
  u16* op = out + (size_t)bz * R * C;
  int r0 = blockIdx.y * 32, c0 = blockIdx.x * 32;
  int tx = threadIdx.x, ty = threadIdx.y; // 32 x 8
#pragma unroll
  for (int j = 0; j < 32; j += 8)
    tile[ty + j][tx] = f2b(ip[(size_t)(r0 + ty + j) * C + (c0 + tx)]);
  __syncthreads();
#pragma unroll
  for (int j = 0; j < 32; j += 8)
    op[(size_t)(c0 + ty + j) * R + (r0 + tx)] = tile[tx][ty + j];
}

// ------- bf16 strided batched transpose: per-bz [R=1024 x C=64] -> [64][1024]
__global__ void tr_v_k(const u16* __restrict__ in, u16* __restrict__ out,
                       int ldi, size_t in_bstride) {
  __shared__ u16 tile[32][34];
  int bz = blockIdx.z;                 // b*HH + h
  const u16* ip = in + (size_t)(bz / HH) * in_bstride + (size_t)(bz % HH) * DDIM;
  u16* op = out + (size_t)bz * DDIM * SS;
  int r0 = blockIdx.y * 32, c0 = blockIdx.x * 32;
  int tx = threadIdx.x, ty = threadIdx.y; // 32 x 8
#pragma unroll
  for (int j = 0; j < 32; j += 8)
    tile[ty + j][tx] = ip[(size_t)(r0 + ty + j) * ldi + (c0 + tx)];
  __syncthreads();
#pragma unroll
  for (int j = 0; j < 32; j += 8)
    op[(size_t)(c0 + ty + j) * SS + (r0 + tx)] = tile[tx][ty + j];
}

// ------- fp32 -> bf16 convert (vector4) -----------------------------------
__global__ void cvt_k(const float* __restrict__ in, u16* __restrict__ out, int n) {
  int i = (blockIdx.x * 256 + threadIdx.x) * 4;
  if (i < n) {
    float4 f = *(const float4*)(in + i);
    u16 o[4] = {f2b(f.x), f2b(f.y), f2b(f.z), f2b(f.w)};
    *(uint64_t*)(out + i) = *(const uint64_t*)o;
  }
}

// ------- bias packing ------------------------------------------------------
__global__ void pack3_k(const float* __restrict__ a, const float* __restrict__ b,
                        const float* __restrict__ c, float* __restrict__ d) {
  int i = blockIdx.x * 256 + threadIdx.x; // grid 9 -> 2304
  if (i < 768) d[i] = a[i];
  else if (i < 1536) d[i] = b[i - 768];
  else d[i] = c[i - 1536];
}
__global__ void pack2_k(const float* __restrict__ a, const float* __restrict__ b,
                        float* __restrict__ d) {
  int i = blockIdx.x * 256 + threadIdx.x; // grid 6 -> 1536
  if (i < 768) d[i] = a[i];
  else d[i] = b[i - 768];
}

// ---------------- LayerNorm over last dim 768 -> bf16 out -------------------
template <typename T>
__global__ __launch_bounds__(256) void layernorm_k(const T* __restrict__ x,
    const float* __restrict__ g, const float* __restrict__ b,
    u16* __restrict__ y) {
  int row = blockIdx.x, t = threadIdx.x;
  const T* xr = x + (size_t)row * EE;
  float v0 = loadf(xr + t), v1 = loadf(xr + t + 256), v2 = loadf(xr + t + 512);
  float s = v0 + v1 + v2;
#pragma unroll
  for (int m = 32; m >= 1; m >>= 1) s += __shfl_xor(s, m);
  __shared__ float red[8];
  int wv = t >> 6, ln = t & 63;
  if (ln == 0) red[wv] = s;
  __syncthreads();
  float mean = (red[0] + red[1] + red[2] + red[3]) * (1.0f / EE);
  float d0 = v0 - mean, d1 = v1 - mean, d2 = v2 - mean;
  float s2 = d0 * d0 + d1 * d1 + d2 * d2;
#pragma unroll
  for (int m = 32; m >= 1; m >>= 1) s2 += __shfl_xor(s2, m);
  if (ln == 0) red[4 + wv] = s2;
  __syncthreads();
  float var = (red[4] + red[5] + red[6] + red[7]) * (1.0f / EE);
  float rstd = rsqrtf(var + 1e-5f);
  u16* yr = y + (size_t)row * EE;
  yr[t]       = f2b(d0 * rstd * g[t]       + b[t]);
  yr[t + 256] = f2b(d1 * rstd * g[t + 256] + b[t + 256]);
  yr[t + 512] = f2b(d2 * rstd * g[t + 512] + b[t + 512]);
}

// ---------------- GEMM 128x128, BK=32, 2-phase dbuf + swizzled LDS ----------
// A bf16 [M][K], Bt bf16 [N][K]. 256 thr = 4 waves (2x2), each 64x64.
// LDS rows 64B: swizzle col8 ^= (row>>1)&3 (16B units) -> all 32 banks, 2-way.
// 2-phase: stage tile s+1, compute tile s, ONE barrier per step (drain after
// compute, so L2 latency hides under MFMA). RESMODE: 0 none,1 f32 res,2 bf16.
template <int RESMODE, bool GELU, typename OutT>
__global__ __launch_bounds__(256) void gemm128_k(
    const u16* __restrict__ A, const u16* __restrict__ Bt,
    const float* __restrict__ bias, const void* __restrict__ res,
    OutT* __restrict__ C, int M, int N, int K) {
  __shared__ u16 As[2][128 * 32];
  __shared__ u16 Bs[2][128 * 32];
  const int bm = blockIdx.y * 128, bn = blockIdx.x * 128;
  const int t = threadIdx.x;
  const int wave = t >> 6, lane = t & 63;
  const int wr = wave >> 1, wc = wave & 1;
  const int g = lane >> 4, li = lane & 15;
  f32x4 acc[4][4] = {};
  const size_t rowskip = (size_t)64 * K;
  // staging: row = t>>2 (0..63, +64), col pre-swizzled on the GLOBAL source
  const int scol = (((t & 3) ^ ((t >> 3) & 3)) * 8);
  const u16* Ag = A + (size_t)(bm + (t >> 2)) * K + scol;
  const u16* Bg = Bt + (size_t)(bn + (t >> 2)) * K + scol;

  gload16(Ag, &As[0][t * 8]);
  gload16(Ag + rowskip, &As[0][2048 + t * 8]);
  gload16(Bg, &Bs[0][t * 8]);
  gload16(Bg + rowskip, &Bs[0][2048 + t * 8]);
  __syncthreads();

  const int nsteps = K >> 5;
  for (int s = 0; s < nsteps; s++) {
    const int cur = s & 1;
    if (s + 1 < nsteps) {
      const int k0 = (s + 1) << 5;
      gload16(Ag + k0, &As[cur ^ 1][t * 8]);
      gload16(Ag + rowskip + k0, &As[cur ^ 1][2048 + t * 8]);
      gload16(Bg + k0, &Bs[cur ^ 1][t * 8]);
      gload16(Bg + rowskip + k0, &Bs[cur ^ 1][2048 + t * 8]);
    }
    short8 af[4], bf[4];
#pragma unroll
    for (int i = 0; i < 4; i++) {
      const int ar = wr * 64 + i * 16 + li;
      af[i] = *(const short8*)(&As[cur][ar * 32 + ((g ^ ((ar >> 1) & 3)) * 8)]);
      const int br = wc * 64 + i * 16 + li;
      bf[i] = *(const short8*)(&Bs[cur][br * 32 + ((g ^ ((br >> 1) & 3)) * 8)]);
    }
#pragma unroll
    for (int mi = 0; mi < 4; mi++)
#pragma unroll
      for (int nj = 0; nj < 4; nj++)
        acc[mi][nj] = mfma16(af[mi], bf[nj], acc[mi][nj]);
    __syncthreads();
  }

#pragma unroll
  for (int mi = 0; mi < 4; mi++)
#pragma unroll
    for (int nj = 0; nj < 4; nj++) {
      int n = bn + wc * 64 + nj * 16 + li;
      float bv = bias[n];
#pragma unroll
      for (int i = 0; i < 4; i++) {
        int m = bm + wr * 64 + mi * 16 + g * 4 + i;
        float val = acc[mi][nj][i] + bv;
        if (GELU) val = gelu_f(val);
        if (RESMODE == 1) val += ((const float*)res)[(size_t)m * N + n];
        else if (RESMODE == 2) val += b2f(((const u16*)res)[(size_t)m * N + n]);
        if constexpr (sizeof(OutT) == 2) C[(size_t)m * N + n] = f2b(val);
        else                             C[(size_t)m * N + n] = val;
      }
    }
}

// ---------------- GEMM 64x64, BK=64, 2-phase dbuf + swizzled LDS ------------
// Grid (N/64, M/64): 4x blocks of 128^2. LDS rows 128B: swizzle (row&7)<<3.
template <int RESMODE, bool GELU, typename OutT>
__global__ __launch_bounds__(256) void gemm64_k(
    const u16* __restrict__ A, const u16* __restrict__ Bt,
    const float* __restrict__ bias, const void* __restrict__ res,
    OutT* __restrict__ C, int M, int N, int K) {
  __shared__ u16 As[2][64 * 64];
  __shared__ u16 Bs[2][64 * 64];
  const int bm = blockIdx.y * 64, bn = blockIdx.x * 64;
  const int t = threadIdx.x;
  const int wave = t >> 6, lane = t & 63;
  const int wr = wave >> 1, wc = wave & 1;   // wave -> 32x32 quadrant
  const int g = lane >> 4, li = lane & 15;
  f32x4 acc[2][2] = {};
  const int srow = t >> 3;                           // 0..31 (+32)
  const int scolz = ((t & 7) * 8) ^ ((srow & 7) << 3);
  const size_t skip32 = (size_t)32 * K;
  const u16* Ag = A + (size_t)(bm + srow) * K + scolz;
  const u16* Bg = Bt + (size_t)(bn + srow) * K + scolz;

  gload16(Ag, &As[0][t * 8]);
  gload16(Ag + skip32, &As[0][2048 + t * 8]);
  gload16(Bg, &Bs[0][t * 8]);
  gload16(Bg + skip32, &Bs[0][2048 + t * 8]);
  __syncthreads();

  const int nsteps = K >> 6;
  for (int s = 0; s < nsteps; s++) {
    const int cur = s & 1;
    if (s + 1 < nsteps) {
      const int k0 = (s + 1) << 6;
      gload16(Ag + k0, &As[cur ^ 1][t * 8]);
      gload16(Ag + skip32 + k0, &As[cur ^ 1][2048 + t * 8]);
      gload16(Bg + k0, &Bs[cur ^ 1][t * 8]);
      gload16(Bg + skip32 + k0, &Bs[cur ^ 1][2048 + t * 8]);
    }
    short8 af[2][2], bf[2][2];
#pragma unroll
    for (int mt = 0; mt < 2; mt++)
#pragma unroll
      for (int kk = 0; kk < 2; kk++) {
        int ar = wr * 32 + mt * 16 + li;
        af[mt][kk] = *(const short8*)(&As[cur][ar * 64 + ((kk * 32 + g * 8) ^ ((ar & 7) << 3))]);
        int br = wc * 32 + mt * 16 + li;
        bf[mt][kk] = *(const short8*)(&Bs[cur][br * 64 + ((kk * 32 + g * 8) ^ ((br & 7) << 3))]);
      }
#pragma unroll
    for (int mt = 0; mt < 2; mt++)
#pragma unroll
      for (int nt = 0; nt < 2; nt++)
#pragma unroll
        for (int kk = 0; kk < 2; kk++)
          acc[mt][nt] = mfma16(af[mt][kk], bf[nt][kk], acc[mt][nt]);
    __syncthreads();
  }

#pragma unroll
  for (int mt = 0; mt < 2; mt++)
#pragma unroll
    for (int nt = 0; nt < 2; nt++) {
      int n = bn + wc * 32 + nt * 16 + li;
      float bv = bias[n];
#pragma unroll
      for (int i = 0; i < 4; i++) {
        int m = bm + wr * 32 + mt * 16 + g * 4 + i;
        float val = acc[mt][nt][i] + bv;
        if (GELU) val = gelu_f(val);
        if (RESMODE == 1) val += ((const float*)res)[(size_t)m * N + n];
        else if (RESMODE == 2) val += b2f(((const u16*)res)[(size_t)m * N + n]);
        if constexpr (sizeof(OutT) == 2) C[(size_t)m * N + n] = f2b(val);
        else                             C[(size_t)m * N + n] = val;
      }
    }
}

// ---------------- Flash attention v4: KVBLK=128, swizzled LDS K/V ----------
// Q/K row layouts with strides ldq/ldk; VT [b*H+h][64 d][1024 t].
// grid (T/64, H, B), 256 threads; wave w owns q rows q0+w*16 .. +15.
template <bool CAUSAL>
__global__ __launch_bounds__(256) void attn4_k(
    const u16* __restrict__ Q, const u16* __restrict__ K,
    const u16* __restrict__ VT, u16* __restrict__ O,
    int ldq, int ldk) {
  int b = blockIdx.z, h = blockIdx.y, q0 = blockIdx.x * 64;
  int tid = threadIdx.x, wave = tid >> 6, lane = tid & 63;
  int g = lane >> 4, li = lane & 15;
  const u16* Qb = Q + (size_t)b * TT * ldq + h * DDIM;
  const u16* Kb = K + (size_t)b * SS * ldk + h * DDIM;
  const u16* Vb = VT + (size_t)(b * HH + h) * DDIM * SS;  // [64][1024]
  u16* Ob = O + (size_t)b * TT * EE + h * DDIM;

  __shared__ u16 Ks[128 * 64];
  __shared__ u16 Vs[64 * 128];
  __shared__ u16 Ps[4][16][132];

  int qrow = q0 + wave * 16 + li;
  short8 qf0 = *(const short8*)(Qb + (size_t)qrow * ldq + g * 8);
  short8 qf1 = *(const short8*)(Qb + (size_t)qrow * ldq + 32 + g * 8);

  f32x4 accO[4] = {};
  float mrow[4], lrow[4];
#pragma unroll
  for (int i = 0; i < 4; i++) { mrow[i] = -1e30f; lrow[i] = 0.f; }

  // staging coords
  const int krow = tid >> 3;                                  // 0..31 (+32j)
  const int vrow = tid >> 4;                                  // 0..15 (+16j)
  const int qmax = q0 + wave * 16 + 15;

  int kvEnd = CAUSAL ? (((q0 + 64 + 127) >> 7) << 7) : SS;
  for (int kv0 = 0; kv0 < kvEnd; kv0 += 128) {
#pragma unroll
    for (int j = 0; j < 4; j++) {
      int kr = j * 32 + krow;
      int kc = ((tid & 7) * 8) ^ ((kr & 7) << 3);
      gload16(Kb + (size_t)(kv0 + kr) * ldk + kc, &Ks[j * 2048 + tid * 8]);
    }
#pragma unroll
    for (int j = 0; j < 4; j++) {
      int vr = j * 16 + vrow;
      int vc = ((tid & 15) * 8) ^ ((vr & 15) << 3);
      gload16(Vb + (size_t)vr * SS + kv0 + vc, &Vs[j * 2048 + tid * 8]);
    }
    __syncthreads();

    if (!CAUSAL || kv0 <= qmax) {
      const bool needMask = CAUSAL && (kv0 + 127 > qmax);
      // S = Q K^T : this wave's 16 q rows x 128 t cols
      f32x4 s[8];
#pragma unroll
      for (int kt = 0; kt < 8; kt++) {
        int kr = kt * 16 + li;
        int sw = (kr & 7) << 3;
        short8 kf0 = *(const short8*)(&Ks[kr * 64 + ((g * 8) ^ sw)]);
        short8 kf1 = *(const short8*)(&Ks[kr * 64 + ((g * 8 + 32) ^ sw)]);
        f32x4 z = {};
        z = mfma16(qf0, kf0, z);
        z = mfma16(qf1, kf1, z);
        s[kt] = z;
      }

      float rmax[4] = {-1e30f, -1e30f, -1e30f, -1e30f};
#pragma unroll
      for (int kt = 0; kt < 8; kt++)
#pragma unroll
        for (int i = 0; i < 4; i++) {
          float sv = s[kt][i] * ATT_SCALE;
          if (needMask) {
            int qi = q0 + wave * 16 + g * 4 + i;
            int ti = kv0 + kt * 16 + li;
            if (ti > qi) sv = -1e30f;
          }
          s[kt][i] = sv;
          rmax[i] = fmaxf(rmax[i], sv);
        }
#pragma unroll
      for (int msk = 1; msk < 16; msk <<= 1)
#pragma unroll
        for (int i = 0; i < 4; i++) rmax[i] = fmaxf(rmax[i], __shfl_xor(rmax[i], msk));

      float corr[4], rsum[4];
#pragma unroll
      for (int i = 0; i < 4; i++) {
        float mn = fmaxf(mrow[i], rmax[i]);
        corr[i] = __expf(mrow[i] - mn);
        mrow[i] = mn;
        rsum[i] = 0.f;
      }
#pragma unroll
      for (int kt = 0; kt < 8; kt++)
#pragma unroll
        for (int i = 0; i < 4; i++) {
          float sv = s[kt][i];
          float p = (sv < -1e29f) ? 0.f : __expf(sv - mrow[i]);
          s[kt][i] = p;
          rsum[i] += p;
        }
#pragma unroll
      for (int msk = 1; msk < 16; msk <<= 1)
#pragma unroll
        for (int i = 0; i < 4; i++) rsum[i] += __shfl_xor(rsum[i], msk);
#pragma unroll
      for (int i = 0; i < 4; i++) lrow[i] = lrow[i] * corr[i] + rsum[i];
#pragma unroll
      for (int dt = 0; dt < 4; dt++)
#pragma unroll
        for (int i = 0; i < 4; i++) accO[dt][i] *= corr[i];

      // P (bf16) -> per-wave LDS, re-read as A-fragments
#pragma unroll
      for (int kt = 0; kt < 8; kt++)
#pragma unroll
        for (int i = 0; i < 4; i++)
          Ps[wave][g * 4 + i][kt * 16 + li] = f2b(s[kt][i]);

#pragma unroll
      for (int tc = 0; tc < 4; tc++) {
        short8 pf = *(const short8*)(&Ps[wave][li][tc * 32 + g * 8]);
#pragma unroll
        for (int dt = 0; dt < 4; dt++) {
          int vr = dt * 16 + li;
          short8 vf = *(const short8*)(&Vs[vr * 128 + ((tc * 32 + g * 8) ^ ((vr & 15) << 3))]);
          accO[dt] = mfma16(pf, vf, accO[dt]);
        }
      }
    }
    __syncthreads();
  }

#pragma unroll
  for (int i = 0; i < 4; i++) {
    float inv = 1.0f / lrow[i];
    int q = q0 + wave * 16 + g * 4 + i;
#pragma unroll
    for (int dt = 0; dt < 4; dt++)
      Ob[(size_t)q * EE + dt * 16 + li] = f2b(accO[dt][i] * inv);
  }
}

// ---------------------------------------------------------------------------
static inline void* wsoff(void* ws, size_t& off, size_t bytes) {
  void* p = (char*)ws + off;
  off += (bytes + 255) & ~(size_t)255;
  return p;
}

extern "C" void kernel_launch(void* const* d_in, const int* in_sizes, int n_in,
                              void* d_out, int out_size, void* d_ws, size_t ws_size,
                              hipStream_t stream) {
  const float* target = (const float*)d_in[0];
  const float* memory = (const float*)d_in[1];
  const float* sa_wq = (const float*)d_in[2];  const float* sa_bq = (const float*)d_in[3];
  const float* sa_wk = (const float*)d_in[4];  const float* sa_bk = (const float*)d_in[5];
  const float* sa_wv = (const float*)d_in[6];  const float* sa_bv = (const float*)d_in[7];
  const float* sa_wo = (const float*)d_in[8];  const float* sa_bo = (const float*)d_in[9];
  const float* ca_wq = (const float*)d_in[10]; const float* ca_bq = (const float*)d_in[11];
  const float* ca_wk = (const float*)d_in[12]; const float* ca_bk = (const float*)d_in[13];
  const float* ca_wv = (const float*)d_in[14]; const float* ca_bv = (const float*)d_in[15];
  const float* ca_wo = (const float*)d_in[16]; const float* ca_bo = (const float*)d_in[17];
  const float* ln1_g = (const float*)d_in[18]; const float* ln1_b = (const float*)d_in[19];
  const float* ln2_g = (const float*)d_in[20]; const float* ln2_b = (const float*)d_in[21];
  const float* ln3_g = (const float*)d_in[22]; const float* ln3_b = (const float*)d_in[23];
  const float* ffn_w1 = (const float*)d_in[24]; const float* ffn_b1 = (const float*)d_in[25];
  const float* ffn_w2 = (const float*)d_in[26]; const float* ffn_b2 = (const float*)d_in[27];

  // ---- workspace (~66 MB) ----
  size_t off = 0;
  const size_t WB = (size_t)EE * EE * 2;           // 1.125 MB
  u16* wqkvT_sa = (u16*)wsoff(d_ws, off, 3 * WB);  // [2304][768]
  u16* wqT_ca   = (u16*)wsoff(d_ws, off, WB);
  u16* wkvT_ca  = (u16*)wsoff(d_ws, off, 2 * WB);  // [1536][768]
  u16* woT_sa   = (u16*)wsoff(d_ws, off, WB);
  u16* woT_ca   = (u16*)wsoff(d_ws, off, WB);
  u16* w1T      = (u16*)wsoff(d_ws, off, (size_t)EE * MM * 2);
  u16* w2T      = (u16*)wsoff(d_ws, off, (size_t)EE * MM * 2);
  float* bsa_qkv = (float*)wsoff(d_ws, off, 2304 * 4);
  float* bca_kv  = (float*)wsoff(d_ws, off, 1536 * 4);
  const size_t AB = (size_t)NROWS * EE * 2;        // 6 MB
  u16* mx2   = (u16*)wsoff(d_ws, off, AB);         // memB (early) / x2 (late)
  u16* lnb   = (u16*)wsoff(d_ws, off, AB);         // S1
  u16* S2    = (u16*)wsoff(d_ws, off, 3 * AB);     // qkv_sa / (qb+kv_ca) / f1 head
  u16* S3    = (u16*)wsoff(d_ws, off, AB);         // attn_out / f1 tail
  u16* x1    = (u16*)wsoff(d_ws, off, AB);
  u16* vt    = (u16*)wsoff(d_ws, off, AB);         // V^T [B*H][64][1024]
  u16* qkv_sa = S2;                                // [4096][2304]
  u16* qb_ca  = S2;                                // [4096][768]
  u16* kv_ca  = S2 + (size_t)NROWS * EE;           // [4096][1536]
  u16* attn_out = S3;                              // [4096][768]
  u16* f1     = S2;                                // [4096][3072]
  u16* memB   = mx2;
  u16* x2     = mx2;

  dim3 tb(32, 8);
  // fp32->bf16 weight transposes: per-head [H][E][D]->[H*D][E]; [R][C]->[C][R]
  transpose_k<<<dim3(2, 24, 12), tb, 0, stream>>>(sa_wq, wqkvT_sa, EE, DDIM);
  transpose_k<<<dim3(2, 24, 12), tb, 0, stream>>>(sa_wk, wqkvT_sa + (size_t)EE * EE, EE, DDIM);
  transpose_k<<<dim3(2, 24, 12), tb, 0, stream>>>(sa_wv, wqkvT_sa + (size_t)2 * EE * EE, EE, DDIM);
  transpose_k<<<dim3(2, 24, 12), tb, 0, stream>>>(ca_wq, wqT_ca, EE, DDIM);
  transpose_k<<<dim3(2, 24, 12), tb, 0, stream>>>(ca_wk, wkvT_ca, EE, DDIM);
  transpose_k<<<dim3(2, 24, 12), tb, 0, stream>>>(ca_wv, wkvT_ca + (size_t)EE * EE, EE, DDIM);
  transpose_k<<<dim3(24, 24, 1), tb, 0, stream>>>(sa_wo, woT_sa, EE, EE);
  transpose_k<<<dim3(24, 24, 1), tb, 0, stream>>>(ca_wo, woT_ca, EE, EE);
  transpose_k<<<dim3(96, 24, 1), tb, 0, stream>>>(ffn_w1, w1T, EE, MM);
  transpose_k<<<dim3(24, 96, 1), tb, 0, stream>>>(ffn_w2, w2T, MM, EE);
  pack3_k<<<9, 256, 0, stream>>>(sa_bq, sa_bk, sa_bv, bsa_qkv);
  pack2_k<<<6, 256, 0, stream>>>(ca_bk, ca_bv, bca_kv);
  cvt_k<<<3072, 256, 0, stream>>>(memory, memB, NROWS * EE);

  // --- self-attention block ---
  layernorm_k<float><<<NROWS, 256, 0, stream>>>(target, ln1_g, ln1_b, lnb);
  gemm128_k<0, false, u16><<<dim3(18, 32), 256, 0, stream>>>(
      lnb, wqkvT_sa, bsa_qkv, nullptr, qkv_sa, NROWS, 3 * EE, EE);
  tr_v_k<<<dim3(2, 32, 48), tb, 0, stream>>>(qkv_sa + 2 * EE, vt, 3 * EE, (size_t)TT * 3 * EE);
  attn4_k<true><<<dim3(16, 12, 4), 256, 0, stream>>>(
      qkv_sa, qkv_sa + EE, vt, attn_out, 3 * EE, 3 * EE);
  gemm64_k<1, false, u16><<<dim3(12, 64), 256, 0, stream>>>(
      attn_out, woT_sa, sa_bo, target, x1, NROWS, EE, EE);

  // --- cross-attention block ---
  layernorm_k<u16><<<NROWS, 256, 0, stream>>>(x1, ln2_g, ln2_b, lnb);
  gemm64_k<0, false, u16><<<dim3(12, 64), 256, 0, stream>>>(
      lnb, wqT_ca, ca_bq, nullptr, qb_ca, NROWS, EE, EE);
  gemm64_k<0, false, u16><<<dim3(24, 64), 256, 0, stream>>>(
      memB, wkvT_ca, bca_kv, nullptr, kv_ca, NROWS, 2 * EE, EE);
  tr_v_k<<<dim3(2, 32, 48), tb, 0, stream>>>(kv_ca + EE, vt, 2 * EE, (size_t)SS * 2 * EE);
  attn4_k<false><<<dim3(16, 12, 4), 256, 0, stream>>>(
      qb_ca, kv_ca, vt, attn_out, EE, 2 * EE);
  gemm64_k<2, false, u16><<<dim3(12, 64), 256, 0, stream>>>(
      attn_out, woT_ca, ca_bo, x1, x2, NROWS, EE, EE);

  // --- FFN block ---
  layernorm_k<u16><<<NROWS, 256, 0, stream>>>(x2, ln3_g, ln3_b, lnb);
  gemm128_k<0, true, u16><<<dim3(24, 32), 256, 0, stream>>>(
      lnb, w1T, ffn_b1, nullptr, f1, NROWS, MM, EE);
  gemm64_k<2, false, float><<<dim3(12, 64), 256, 0, stream>>>(
      f1, w2T, ffn_b2, x2, (float*)d_out, NROWS, EE, MM);
}